// Round 1
// baseline (1159.812 us; speedup 1.0000x reference)
//
#include <hip/hip_runtime.h>

#define NB 8
#define NV 12288
#define NE 147456
#define CFM 384
#define CU 61
#define FEPS 0.005f

// ---------- ws layout (floats) ----------
// pf    : NB*4096*64   = 2097152   (conv-projected feature map, 61 used, pad 64)
// xfeat : NB*NV*64     = 6291456   (GNN input features)
// agg1  : NB*NV*64     = 6291456
// h     : NB*NV*128    = 12582912
// agg2  : NB*NV*128    = 12582912
// deg   : NV           = 12288
// cwT   : 384*64       = 24576     (transposed conv_w, zero padded)
// total ~159.5 MB

// transpose conv_w (61,384) -> cwT (384,64), zero-pad o>=61
__global__ void k_wt(const float* __restrict__ cw, float* __restrict__ cwT) {
    int idx = blockIdx.x * 256 + threadIdx.x;
    if (idx >= CFM * 64) return;
    int c = idx >> 6, o = idx & 63;
    cwT[idx] = (o < CU) ? cw[o * CFM + c] : 0.f;
}

// pf[b][p][o] = sum_c cwT[c][o] * fm[b][c][p]
__global__ void k_conv(const float* __restrict__ fm, const float* __restrict__ cwT,
                       float* __restrict__ pf) {
    int idx = blockIdx.x * 256 + threadIdx.x;   // NB*4096 = 32768
    int b = idx >> 12, p = idx & 4095;
    const float* f = fm + ((size_t)b * CFM) * 4096 + p;
    float acc[CU];
#pragma unroll
    for (int o = 0; o < CU; o++) acc[o] = 0.f;
    for (int c = 0; c < CFM; c++) {
        float fv = f[(size_t)c * 4096];
        const float* w = cwT + c * 64;   // uniform index -> scalar loads
#pragma unroll
        for (int o = 0; o < CU; o++) acc[o] = fmaf(fv, w[o], acc[o]);
    }
    float* out = pf + (size_t)idx * 64;
#pragma unroll
    for (int o = 0; o < CU; o++) out[o] = acc[o];
}

// per-vertex: project, depth-sample visibility, feature-sample, build xfeat row
// 16 lanes per vertex, 16 vertices per 256-block
__global__ void k_sample(const float* __restrict__ depth, const float* __restrict__ pf,
                         const float* __restrict__ verts, const float* __restrict__ fz,
                         const float* __restrict__ cz, const float* __restrict__ convb,
                         float* __restrict__ xfeat) {
    int t = blockIdx.x * 256 + threadIdx.x;
    int gid = t >> 4;                 // b*NV+v
    int ln = t & 15;
    int b = gid / NV;
    const float* vp = verts + (size_t)gid * 3;
    float vx = vp[0], vy = vp[1], vz = vp[2];
    float fzb = fz[b], czb = cz[2 * b];
    float gx = fzb * vx + czb;
    float gy = fzb * vy + czb;
    float gz = fzb * (vz + 100.f);

    // ---- depth bilinear (H=W=128), zero padding
    float px = (gx + 1.f) * 64.f - 0.5f;
    float py = (gy + 1.f) * 64.f - 0.5f;
    float fx0 = floorf(px), fy0 = floorf(py);
    float wx1 = px - fx0, wy1 = py - fy0, wx0 = 1.f - wx1, wy0 = 1.f - wy1;
    int x0 = (int)fx0, y0 = (int)fy0;
    const float* dmb = depth + (size_t)b * 128 * 128;
    float d00 = 0.f, d01 = 0.f, d10 = 0.f, d11 = 0.f;
    bool X0 = (x0 >= 0 && x0 < 128), X1 = (x0 + 1 >= 0 && x0 + 1 < 128);
    bool Y0 = (y0 >= 0 && y0 < 128), Y1 = (y0 + 1 >= 0 && y0 + 1 < 128);
    int xa = min(max(x0, 0), 127), xb = min(max(x0 + 1, 0), 127);
    int ya = min(max(y0, 0), 127), yb = min(max(y0 + 1, 0), 127);
    if (Y0 && X0) d00 = dmb[ya * 128 + xa];
    if (Y0 && X1) d01 = dmb[ya * 128 + xb];
    if (Y1 && X0) d10 = dmb[yb * 128 + xa];
    if (Y1 && X1) d11 = dmb[yb * 128 + xb];
    float sd = d00 * wy0 * wx0 + d01 * wy0 * wx1 + d10 * wy1 * wx0 + d11 * wy1 * wx1;
    float vis = (fabsf(sd - gz) < FEPS) ? 1.f : 0.f;

    // ---- feature bilinear (H=W=64) on pf (position-major, 64ch rows)
    float qx = (gx + 1.f) * 32.f - 0.5f;
    float qy = (gy + 1.f) * 32.f - 0.5f;
    float gx0 = floorf(qx), gy0 = floorf(qy);
    float ax1 = qx - gx0, ay1 = qy - gy0, ax0 = 1.f - ax1, ay0 = 1.f - ay1;
    int cx0 = (int)gx0, cy0 = (int)gy0;
    bool FX0 = (cx0 >= 0 && cx0 < 64), FX1 = (cx0 + 1 >= 0 && cx0 + 1 < 64);
    bool FY0 = (cy0 >= 0 && cy0 < 64), FY1 = (cy0 + 1 >= 0 && cy0 + 1 < 64);
    int fxa = min(max(cx0, 0), 63), fxb = min(max(cx0 + 1, 0), 63);
    int fya = min(max(cy0, 0), 63), fyb = min(max(cy0 + 1, 0), 63);
    float m00 = (FY0 && FX0) ? ay0 * ax0 : 0.f;
    float m01 = (FY0 && FX1) ? ay0 * ax1 : 0.f;
    float m10 = (FY1 && FX0) ? ay1 * ax0 : 0.f;
    float m11 = (FY1 && FX1) ? ay1 * ax1 : 0.f;
    const float* pfb = pf + (size_t)b * 4096 * 64;
    const float* p00 = pfb + ((size_t)fya * 64 + fxa) * 64;
    const float* p01 = pfb + ((size_t)fya * 64 + fxb) * 64;
    const float* p10 = pfb + ((size_t)fyb * 64 + fxa) * 64;
    const float* p11 = pfb + ((size_t)fyb * 64 + fxb) * 64;

    float* xr = xfeat + (size_t)gid * 64;
#pragma unroll
    for (int j = 0; j < 4; j++) {
        int c = ln + 16 * j;
        if (c < CU) {
            float val = m00 * p00[c] + m01 * p01[c] + m10 * p10[c] + m11 * p11[c];
            xr[c] = vis * val + convb[c];
        } else {
            xr[c] = vp[c - CU];   // c in {61,62,63} -> vertex coords
        }
    }
}

__global__ void k_deg(const int* __restrict__ erow, float* __restrict__ deg) {
    int e = blockIdx.x * 256 + threadIdx.x;
    if (e < NE) atomicAdd(&deg[erow[e]], 1.f);
}

// scatter-add aggregation, F=64: 64 lanes per edge, loop over batches
__global__ void k_agg64(const int* __restrict__ erow, const int* __restrict__ ecol,
                        const float* __restrict__ src, float* __restrict__ dst) {
    int t = blockIdx.x * 256 + threadIdx.x;
    int e = t >> 6, f = t & 63;
    if (e >= NE) return;
    int r = erow[e], c = ecol[e];
#pragma unroll
    for (int b = 0; b < NB; b++) {
        float vv = src[((size_t)b * NV + c) * 64 + f];
        atomicAdd(&dst[((size_t)b * NV + r) * 64 + f], vv);
    }
}

// scatter-add aggregation, F=128: 128 lanes per edge
__global__ void k_agg128(const int* __restrict__ erow, const int* __restrict__ ecol,
                         const float* __restrict__ src, float* __restrict__ dst) {
    int t = blockIdx.x * 256 + threadIdx.x;
    int e = t >> 7, f = t & 127;
    if (e >= NE) return;
    int r = erow[e], c = ecol[e];
#pragma unroll
    for (int b = 0; b < NB; b++) {
        float vv = src[((size_t)b * NV + c) * 128 + f];
        atomicAdd(&dst[((size_t)b * NV + r) * 128 + f], vv);
    }
}

// h = relu((agg1/deg) @ W1 + b1); 2 threads per vertex (64 outputs each)
__global__ void k_mlp1(const float* __restrict__ agg1, const float* __restrict__ deg,
                       const float* __restrict__ W1, const float* __restrict__ b1,
                       float* __restrict__ h) {
    int lv = threadIdx.x & 127, half = threadIdx.x >> 7;  // half uniform per wave
    int gid = blockIdx.x * 128 + lv;                      // b*NV+v
    int v = gid % NV;
    float dinv = 1.f / fmaxf(deg[v], 1.f);
    const float* ar = agg1 + (size_t)gid * 64;
    float acc[64];
#pragma unroll
    for (int o = 0; o < 64; o++) acc[o] = 0.f;
    for (int k = 0; k < 64; k++) {
        float xv = ar[k] * dinv;
        const float* w = W1 + k * 128 + half * 64;   // wave-uniform -> scalar loads
#pragma unroll
        for (int o = 0; o < 64; o++) acc[o] = fmaf(xv, w[o], acc[o]);
    }
    float* hr = h + (size_t)gid * 128 + half * 64;
    const float* bb = b1 + half * 64;
#pragma unroll
    for (int o = 0; o < 64; o++) hr[o] = fmaxf(acc[o] + bb[o], 0.f);
}

// x_out = (agg2/deg) @ W2; dv = h @ W_dv; emit 38-wide output rows
__global__ void k_final(const float* __restrict__ agg2, const float* __restrict__ h,
                        const float* __restrict__ deg, const float* __restrict__ verts,
                        const float* __restrict__ W2, const float* __restrict__ Wdv,
                        float* __restrict__ out) {
    int gid = blockIdx.x * 256 + threadIdx.x;   // b*NV+v
    int v = gid % NV;
    float dinv = 1.f / fmaxf(deg[v], 1.f);
    const float* ar = agg2 + (size_t)gid * 128;
    const float* hr = h + (size_t)gid * 128;
    float acc[32];
    float dv0 = 0.f, dv1 = 0.f, dv2 = 0.f;
#pragma unroll
    for (int o = 0; o < 32; o++) acc[o] = 0.f;
    for (int k = 0; k < 128; k++) {
        float av = ar[k] * dinv;
        float hv = hr[k];
        const float* w2 = Wdv + k * 3;
#pragma unroll
        for (int o = 0; o < 32; o++) acc[o] = fmaf(av, W2[k * 32 + o], acc[o]);
        dv0 = fmaf(hv, w2[0], dv0);
        dv1 = fmaf(hv, w2[1], dv1);
        dv2 = fmaf(hv, w2[2], dv2);
    }
    const float* vp = verts + (size_t)gid * 3;
    float* orow = out + (size_t)gid * 38;
#pragma unroll
    for (int o = 0; o < 32; o++) orow[o] = acc[o];
    orow[32] = (vp[0] + dv0) * 1000.f;
    orow[33] = (vp[1] + dv1) * 1000.f;
    orow[34] = (vp[2] + dv2) * 1000.f;
    orow[35] = dv0 * 1000.f;
    orow[36] = dv1 * 1000.f;
    orow[37] = dv2 * 1000.f;
}

extern "C" void kernel_launch(void* const* d_in, const int* in_sizes, int n_in,
                              void* d_out, int out_size, void* d_ws, size_t ws_size,
                              hipStream_t stream) {
    const float* fm  = (const float*)d_in[0];   // feature_map (B,384,64,64)
    const float* dm  = (const float*)d_in[1];   // depth_map (B,1,128,128)
    const float* vt  = (const float*)d_in[2];   // vertices (B,V,3)
    const float* fz  = (const float*)d_in[3];   // (B,)
    const float* cz  = (const float*)d_in[4];   // (B,2)
    const float* cw  = (const float*)d_in[5];   // conv_w (61,384)
    const float* cb  = (const float*)d_in[6];   // conv_b (61,)
    const float* W1  = (const float*)d_in[7];   // (64,128)
    const float* b1  = (const float*)d_in[8];   // (128,)
    const float* W2  = (const float*)d_in[9];   // (128,32)
    const float* Wdv = (const float*)d_in[10];  // (128,3)
    const int* erow  = (const int*)d_in[11];
    const int* ecol  = (const int*)d_in[12];
    float* out = (float*)d_out;

    float* ws    = (float*)d_ws;
    float* pf    = ws;                  // 2097152
    float* xfeat = pf + 2097152;        // 6291456
    float* agg1  = xfeat + 6291456;     // 6291456
    float* hbuf  = agg1 + 6291456;      // 12582912
    float* agg2  = hbuf + 12582912;     // 12582912
    float* deg   = agg2 + 12582912;     // 12288
    float* cwT   = deg + 12288;         // 24576

    hipMemsetAsync(agg1, 0, (size_t)6291456 * 4, stream);
    hipMemsetAsync(agg2, 0, (size_t)12582912 * 4, stream);
    hipMemsetAsync(deg, 0, (size_t)12288 * 4, stream);

    k_wt<<<96, 256, 0, stream>>>(cw, cwT);
    k_conv<<<128, 256, 0, stream>>>(fm, cwT, pf);
    k_sample<<<6144, 256, 0, stream>>>(dm, pf, vt, fz, cz, cb, xfeat);
    k_deg<<<576, 256, 0, stream>>>(erow, deg);
    k_agg64<<<36864, 256, 0, stream>>>(erow, ecol, xfeat, agg1);
    k_mlp1<<<768, 256, 0, stream>>>(agg1, deg, W1, b1, hbuf);
    k_agg128<<<73728, 256, 0, stream>>>(erow, ecol, hbuf, agg2);
    k_final<<<384, 256, 0, stream>>>(agg2, hbuf, deg, vt, W2, Wdv, out);
}

// Round 2
// 471.250 us; speedup vs baseline: 2.4611x; 2.4611x over previous
//
#include <hip/hip_runtime.h>

#define NB 8
#define NV 12288
#define NE 147456
#define CFM 384
#define CU 61
#define FEPS 0.005f

// ---------- ws layout ----------
// pf    : NB*4096*64 f  = 2097152   (conv-projected feature map, [b][p][64])
// xfeat : NV*NB*64 f    = 6291456   (vertex-major GNN input)
// agg1d : NV*NB*64 f    = 6291456   (gathered+divided)
// y2    : NV*NB*32 f    = 3145728   (h @ W2, vertex-major)
// cwT   : 384*64 f      = 24576
// counts: NV int, offs: NV int, cursor: NV int, csr: NE int

// transpose conv_w (61,384) -> cwT (384,64), zero-pad o>=61
__global__ void k_wt(const float* __restrict__ cw, float* __restrict__ cwT) {
    int idx = blockIdx.x * 256 + threadIdx.x;
    if (idx >= CFM * 64) return;
    int c = idx >> 6, o = idx & 63;
    cwT[idx] = (o < CU) ? cw[o * CFM + c] : 0.f;
}

// pf[b][p][o] = sum_c cwT[c][o] * fm[b][c][p]
__global__ void k_conv(const float* __restrict__ fm, const float* __restrict__ cwT,
                       float* __restrict__ pf) {
    int idx = blockIdx.x * 256 + threadIdx.x;   // NB*4096 = 32768
    int b = idx >> 12, p = idx & 4095;
    const float* f = fm + ((size_t)b * CFM) * 4096 + p;
    float acc[CU];
#pragma unroll
    for (int o = 0; o < CU; o++) acc[o] = 0.f;
#pragma unroll 4
    for (int c = 0; c < CFM; c++) {
        float fv = f[(size_t)c * 4096];
        const float* w = cwT + c * 64;   // uniform index -> scalar loads
#pragma unroll
        for (int o = 0; o < CU; o++) acc[o] = fmaf(fv, w[o], acc[o]);
    }
    float* out = pf + (size_t)idx * 64;
#pragma unroll
    for (int o = 0; o < CU; o++) out[o] = acc[o];
}

// per-vertex projection + depth visibility + feature bilinear -> xfeat[v][b][64]
__global__ void k_sample(const float* __restrict__ depth, const float* __restrict__ pf,
                         const float* __restrict__ verts, const float* __restrict__ fz,
                         const float* __restrict__ cz, const float* __restrict__ convb,
                         float* __restrict__ xfeat) {
    int t = blockIdx.x * 256 + threadIdx.x;
    int gid = t >> 4;                 // b*NV+v
    int ln = t & 15;
    int b = gid / NV;
    int v = gid - b * NV;
    const float* vp = verts + (size_t)gid * 3;
    float vx = vp[0], vy = vp[1], vz = vp[2];
    float fzb = fz[b], czb = cz[2 * b];
    float gx = fzb * vx + czb;
    float gy = fzb * vy + czb;
    float gz = fzb * (vz + 100.f);

    // depth bilinear (128x128), zero padding
    float px = (gx + 1.f) * 64.f - 0.5f;
    float py = (gy + 1.f) * 64.f - 0.5f;
    float fx0 = floorf(px), fy0 = floorf(py);
    float wx1 = px - fx0, wy1 = py - fy0, wx0 = 1.f - wx1, wy0 = 1.f - wy1;
    int x0 = (int)fx0, y0 = (int)fy0;
    const float* dmb = depth + (size_t)b * 128 * 128;
    float d00 = 0.f, d01 = 0.f, d10 = 0.f, d11 = 0.f;
    bool X0 = (x0 >= 0 && x0 < 128), X1 = (x0 + 1 >= 0 && x0 + 1 < 128);
    bool Y0 = (y0 >= 0 && y0 < 128), Y1 = (y0 + 1 >= 0 && y0 + 1 < 128);
    int xa = min(max(x0, 0), 127), xb = min(max(x0 + 1, 0), 127);
    int ya = min(max(y0, 0), 127), yb = min(max(y0 + 1, 0), 127);
    if (Y0 && X0) d00 = dmb[ya * 128 + xa];
    if (Y0 && X1) d01 = dmb[ya * 128 + xb];
    if (Y1 && X0) d10 = dmb[yb * 128 + xa];
    if (Y1 && X1) d11 = dmb[yb * 128 + xb];
    float sd = d00 * wy0 * wx0 + d01 * wy0 * wx1 + d10 * wy1 * wx0 + d11 * wy1 * wx1;
    float vis = (fabsf(sd - gz) < FEPS) ? 1.f : 0.f;

    // feature bilinear (64x64) on pf
    float qx = (gx + 1.f) * 32.f - 0.5f;
    float qy = (gy + 1.f) * 32.f - 0.5f;
    float gx0 = floorf(qx), gy0 = floorf(qy);
    float ax1 = qx - gx0, ay1 = qy - gy0, ax0 = 1.f - ax1, ay0 = 1.f - ay1;
    int cx0 = (int)gx0, cy0 = (int)gy0;
    bool FX0 = (cx0 >= 0 && cx0 < 64), FX1 = (cx0 + 1 >= 0 && cx0 + 1 < 64);
    bool FY0 = (cy0 >= 0 && cy0 < 64), FY1 = (cy0 + 1 >= 0 && cy0 + 1 < 64);
    int fxa = min(max(cx0, 0), 63), fxb = min(max(cx0 + 1, 0), 63);
    int fya = min(max(cy0, 0), 63), fyb = min(max(cy0 + 1, 0), 63);
    float m00 = (FY0 && FX0) ? ay0 * ax0 : 0.f;
    float m01 = (FY0 && FX1) ? ay0 * ax1 : 0.f;
    float m10 = (FY1 && FX0) ? ay1 * ax0 : 0.f;
    float m11 = (FY1 && FX1) ? ay1 * ax1 : 0.f;
    const float* pfb = pf + (size_t)b * 4096 * 64;
    const float* p00 = pfb + ((size_t)fya * 64 + fxa) * 64;
    const float* p01 = pfb + ((size_t)fya * 64 + fxb) * 64;
    const float* p10 = pfb + ((size_t)fyb * 64 + fxa) * 64;
    const float* p11 = pfb + ((size_t)fyb * 64 + fxb) * 64;

    float* xr = xfeat + ((size_t)v * NB + b) * 64;
#pragma unroll
    for (int j = 0; j < 4; j++) {
        int c = ln + 16 * j;
        if (c < CU) {
            float val = m00 * p00[c] + m01 * p01[c] + m10 * p10[c] + m11 * p11[c];
            xr[c] = vis * val + convb[c];
        } else {
            xr[c] = vp[c - CU];
        }
    }
}

// ---- CSR build ----
__global__ void k_count(const int* __restrict__ erow, int* __restrict__ counts) {
    int e = blockIdx.x * 256 + threadIdx.x;
    if (e < NE) atomicAdd(&counts[erow[e]], 1);
}

// exclusive prefix sum over NV=12288 counts; 1 block x 1024, 12 bins/thread
__global__ void k_scan(const int* __restrict__ counts, int* __restrict__ offs) {
    __shared__ int part[1024];
    int t = threadIdx.x;
    int base = t * 12;
    int local[12];
    int s = 0;
#pragma unroll
    for (int i = 0; i < 12; i++) { local[i] = s; s += counts[base + i]; }
    part[t] = s;
    __syncthreads();
    for (int off = 1; off < 1024; off <<= 1) {
        int v = (t >= off) ? part[t - off] : 0;
        __syncthreads();
        part[t] += v;
        __syncthreads();
    }
    int prefix = part[t] - s;   // exclusive
#pragma unroll
    for (int i = 0; i < 12; i++) offs[base + i] = prefix + local[i];
}

__global__ void k_fill(const int* __restrict__ erow, const int* __restrict__ ecol,
                       const int* __restrict__ offs, int* __restrict__ cursor,
                       int* __restrict__ csr) {
    int e = blockIdx.x * 256 + threadIdx.x;
    if (e >= NE) return;
    int r = erow[e];
    int pos = offs[r] + atomicAdd(&cursor[r], 1);
    csr[pos] = ecol[e];
}

// gather-agg 64-wide over all 8 batches; one wave per dest vertex; fold 1/deg
__global__ void k_agg1(const int* __restrict__ counts, const int* __restrict__ offs,
                       const int* __restrict__ csr, const float* __restrict__ xfeat,
                       float* __restrict__ agg1d) {
    int wid = (blockIdx.x * 256 + threadIdx.x) >> 6;   // vertex
    int l = threadIdx.x & 63;
    if (wid >= NV) return;
    int beg = offs[wid], n = counts[wid];
    float a0x = 0.f, a0y = 0.f, a0z = 0.f, a0w = 0.f;
    float a1x = 0.f, a1y = 0.f, a1z = 0.f, a1w = 0.f;
    for (int j = 0; j < n; j++) {
        int c = csr[beg + j];
        const float4* src = (const float4*)(xfeat + (size_t)c * 512);
        float4 u = src[l];
        float4 w = src[64 + l];
        a0x += u.x; a0y += u.y; a0z += u.z; a0w += u.w;
        a1x += w.x; a1y += w.y; a1z += w.z; a1w += w.w;
    }
    float dinv = 1.f / fmaxf((float)n, 1.f);
    float4* dst = (float4*)(agg1d + (size_t)wid * 512);
    dst[l]      = make_float4(a0x * dinv, a0y * dinv, a0z * dinv, a0w * dinv);
    dst[64 + l] = make_float4(a1x * dinv, a1y * dinv, a1z * dinv, a1w * dinv);
}

// fused MLP: h = relu(agg1d@W1+b1) in LDS; y2 = h@W2; dv = h@Wdv; out tail
// block = 128 threads, 64 rows (row = v*8+b), half = tid>>6 (wave-uniform)
__global__ void k_mlp(const float* __restrict__ agg1d, const float* __restrict__ W1,
                      const float* __restrict__ b1, const float* __restrict__ W2,
                      const float* __restrict__ Wdv, const float* __restrict__ verts,
                      float* __restrict__ y2, float* __restrict__ out) {
    __shared__ float hlds[128][64];   // [k][row]
    int tid = threadIdx.x;
    int r = tid & 63, half = tid >> 6;
    int row = blockIdx.x * 64 + r;    // v*8+b
    const float4* ar4 = (const float4*)(agg1d + (size_t)row * 64);
    float acc[64];
#pragma unroll
    for (int o = 0; o < 64; o++) acc[o] = 0.f;
    for (int kk = 0; kk < 16; kk++) {
        float4 xv4 = ar4[kk];
        const float* w0 = W1 + (kk * 4 + 0) * 128 + half * 64;
        const float* w1 = W1 + (kk * 4 + 1) * 128 + half * 64;
        const float* w2 = W1 + (kk * 4 + 2) * 128 + half * 64;
        const float* w3 = W1 + (kk * 4 + 3) * 128 + half * 64;
#pragma unroll
        for (int o = 0; o < 64; o++) {
            float t = fmaf(xv4.x, w0[o], acc[o]);
            t = fmaf(xv4.y, w1[o], t);
            t = fmaf(xv4.z, w2[o], t);
            acc[o] = fmaf(xv4.w, w3[o], t);
        }
    }
#pragma unroll
    for (int o = 0; o < 64; o++)
        hlds[half * 64 + o][r] = fmaxf(acc[o] + b1[half * 64 + o], 0.f);
    __syncthreads();

    float y[16];
#pragma unroll
    for (int o = 0; o < 16; o++) y[o] = 0.f;
    float d0 = 0.f, d1 = 0.f, d2 = 0.f;
    for (int k = 0; k < 128; k++) {
        float hv = hlds[k][r];
        const float* w2 = W2 + k * 32 + half * 16;
#pragma unroll
        for (int o = 0; o < 16; o++) y[o] = fmaf(hv, w2[o], y[o]);
        d0 = fmaf(hv, Wdv[k * 3 + 0], d0);
        d1 = fmaf(hv, Wdv[k * 3 + 1], d1);
        d2 = fmaf(hv, Wdv[k * 3 + 2], d2);
    }
    float* yr = y2 + (size_t)row * 32 + half * 16;
#pragma unroll
    for (int o = 0; o < 16; o++) yr[o] = y[o];

    if (half == 0) {
        int v = row >> 3, b = row & 7;
        const float* vp = verts + ((size_t)b * NV + v) * 3;
        float* orow = out + ((size_t)b * NV + v) * 38;
        orow[32] = (vp[0] + d0) * 1000.f;
        orow[33] = (vp[1] + d1) * 1000.f;
        orow[34] = (vp[2] + d2) * 1000.f;
        orow[35] = d0 * 1000.f;
        orow[36] = d1 * 1000.f;
        orow[37] = d2 * 1000.f;
    }
}

// gather-agg over y2 (32-wide x 8 batches = 256 floats/vertex); write out[0..31]
__global__ void k_agg2(const int* __restrict__ counts, const int* __restrict__ offs,
                       const int* __restrict__ csr, const float* __restrict__ y2,
                       float* __restrict__ out) {
    int wid = (blockIdx.x * 256 + threadIdx.x) >> 6;   // vertex
    int l = threadIdx.x & 63;
    if (wid >= NV) return;
    int beg = offs[wid], n = counts[wid];
    float ax = 0.f, ay = 0.f, az = 0.f, aw = 0.f;
    for (int j = 0; j < n; j++) {
        int c = csr[beg + j];
        const float4* src = (const float4*)(y2 + (size_t)c * 256);
        float4 u = src[l];
        ax += u.x; ay += u.y; az += u.z; aw += u.w;
    }
    float dinv = 1.f / fmaxf((float)n, 1.f);
    int b = l >> 3, o = (l & 7) * 4;
    float* orow = out + ((size_t)b * NV + wid) * 38 + o;
    orow[0] = ax * dinv;
    orow[1] = ay * dinv;
    orow[2] = az * dinv;
    orow[3] = aw * dinv;
}

extern "C" void kernel_launch(void* const* d_in, const int* in_sizes, int n_in,
                              void* d_out, int out_size, void* d_ws, size_t ws_size,
                              hipStream_t stream) {
    const float* fm  = (const float*)d_in[0];
    const float* dm  = (const float*)d_in[1];
    const float* vt  = (const float*)d_in[2];
    const float* fz  = (const float*)d_in[3];
    const float* cz  = (const float*)d_in[4];
    const float* cw  = (const float*)d_in[5];
    const float* cb  = (const float*)d_in[6];
    const float* W1  = (const float*)d_in[7];
    const float* b1  = (const float*)d_in[8];
    const float* W2  = (const float*)d_in[9];
    const float* Wdv = (const float*)d_in[10];
    const int* erow  = (const int*)d_in[11];
    const int* ecol  = (const int*)d_in[12];
    float* out = (float*)d_out;

    float* ws    = (float*)d_ws;
    float* pf    = ws;                   // 2097152
    float* xfeat = pf + 2097152;         // 6291456
    float* agg1d = xfeat + 6291456;      // 6291456
    float* y2    = agg1d + 6291456;      // 3145728
    float* cwT   = y2 + 3145728;         // 24576
    int* counts  = (int*)(cwT + 24576);  // 12288
    int* offs    = counts + 12288;       // 12288
    int* cursor  = offs + 12288;         // 12288
    int* csr     = cursor + 12288;       // 147456

    hipMemsetAsync(counts, 0, 12288 * sizeof(int), stream);
    hipMemsetAsync(cursor, 0, 12288 * sizeof(int), stream);

    k_wt<<<96, 256, 0, stream>>>(cw, cwT);
    k_conv<<<128, 256, 0, stream>>>(fm, cwT, pf);
    k_sample<<<6144, 256, 0, stream>>>(dm, pf, vt, fz, cz, cb, xfeat);
    k_count<<<576, 256, 0, stream>>>(erow, counts);
    k_scan<<<1, 1024, 0, stream>>>(counts, offs);
    k_fill<<<576, 256, 0, stream>>>(erow, ecol, offs, cursor, csr);
    k_agg1<<<3072, 256, 0, stream>>>(counts, offs, csr, xfeat, agg1d);
    k_mlp<<<1536, 128, 0, stream>>>(agg1d, W1, b1, W2, Wdv, vt, y2, out);
    k_agg2<<<3072, 256, 0, stream>>>(counts, offs, csr, y2, out);
}

// Round 3
// 420.888 us; speedup vs baseline: 2.7556x; 1.1197x over previous
//
#include <hip/hip_runtime.h>

#define NB 8
#define NV 12288
#define NE 147456
#define CFM 384
#define CU 61
#define FEPS 0.005f

// ---------- ws layout ----------
// pf    : NB*4096*64 f  = 2097152   (conv-projected feature map, [b][p][64])
// xfeat : NV*NB*64 f    = 6291456   (vertex-major GNN input)
// agg1d : NV*NB*64 f    = 6291456   (gathered+divided)
// y2    : NV*NB*32 f    = 3145728   (h @ W2, vertex-major)
// cwT   : 384*64 f      = 24576
// counts: NV int, offs: NV int, cursor: NV int, csr: NE int

// transpose conv_w (61,384) -> cwT (384,64), zero-pad o>=61
__global__ void k_wt(const float* __restrict__ cw, float* __restrict__ cwT) {
    int idx = blockIdx.x * 256 + threadIdx.x;
    if (idx >= CFM * 64) return;
    int c = idx >> 6, o = idx & 63;
    cwT[idx] = (o < CU) ? cw[o * CFM + c] : 0.f;
}

// pf[b][p][o] = sum_c cwT[c][o] * fm[b][c][p]
// block = 128 threads = 64 positions x 2 channel-groups (g wave-uniform)
__global__ void k_conv(const float* __restrict__ fm, const float* __restrict__ cwT,
                       float* __restrict__ pf) {
    __shared__ float part[64][CU];
    int tid = threadIdx.x;
    int r = tid & 63, g = tid >> 6;              // g in {0,1}, wave-uniform
    int idx = blockIdx.x * 64 + r;               // NB*4096 = 32768 positions
    int b = idx >> 12, p = idx & 4095;
    const float* f = fm + ((size_t)b * CFM + g * 192) * 4096 + p;
    float acc[CU];
#pragma unroll
    for (int o = 0; o < CU; o++) acc[o] = 0.f;
#pragma unroll 4
    for (int c = 0; c < 192; c++) {
        float fv = f[(size_t)c * 4096];
        const float* w = cwT + (g * 192 + c) * 64;   // uniform -> scalar loads
#pragma unroll
        for (int o = 0; o < CU; o++) acc[o] = fmaf(fv, w[o], acc[o]);
    }
    if (g == 1) {
#pragma unroll
        for (int o = 0; o < CU; o++) part[r][o] = acc[o];
    }
    __syncthreads();
    if (g == 0) {
        float* outp = pf + (size_t)idx * 64;
#pragma unroll
        for (int o = 0; o < CU; o++) outp[o] = acc[o] + part[r][o];
    }
}

// per-vertex projection + depth visibility + feature bilinear -> xfeat[v][b][64]
__global__ void k_sample(const float* __restrict__ depth, const float* __restrict__ pf,
                         const float* __restrict__ verts, const float* __restrict__ fz,
                         const float* __restrict__ cz, const float* __restrict__ convb,
                         float* __restrict__ xfeat) {
    int t = blockIdx.x * 256 + threadIdx.x;
    int gid = t >> 4;                 // b*NV+v
    int ln = t & 15;
    int b = gid / NV;
    int v = gid - b * NV;
    const float* vp = verts + (size_t)gid * 3;
    float vx = vp[0], vy = vp[1], vz = vp[2];
    float fzb = fz[b], czb = cz[2 * b];
    float gx = fzb * vx + czb;
    float gy = fzb * vy + czb;
    float gz = fzb * (vz + 100.f);

    // depth bilinear (128x128), zero padding
    float px = (gx + 1.f) * 64.f - 0.5f;
    float py = (gy + 1.f) * 64.f - 0.5f;
    float fx0 = floorf(px), fy0 = floorf(py);
    float wx1 = px - fx0, wy1 = py - fy0, wx0 = 1.f - wx1, wy0 = 1.f - wy1;
    int x0 = (int)fx0, y0 = (int)fy0;
    const float* dmb = depth + (size_t)b * 128 * 128;
    float d00 = 0.f, d01 = 0.f, d10 = 0.f, d11 = 0.f;
    bool X0 = (x0 >= 0 && x0 < 128), X1 = (x0 + 1 >= 0 && x0 + 1 < 128);
    bool Y0 = (y0 >= 0 && y0 < 128), Y1 = (y0 + 1 >= 0 && y0 + 1 < 128);
    int xa = min(max(x0, 0), 127), xb = min(max(x0 + 1, 0), 127);
    int ya = min(max(y0, 0), 127), yb = min(max(y0 + 1, 0), 127);
    if (Y0 && X0) d00 = dmb[ya * 128 + xa];
    if (Y0 && X1) d01 = dmb[ya * 128 + xb];
    if (Y1 && X0) d10 = dmb[yb * 128 + xa];
    if (Y1 && X1) d11 = dmb[yb * 128 + xb];
    float sd = d00 * wy0 * wx0 + d01 * wy0 * wx1 + d10 * wy1 * wx0 + d11 * wy1 * wx1;
    float vis = (fabsf(sd - gz) < FEPS) ? 1.f : 0.f;

    // feature bilinear (64x64) on pf
    float qx = (gx + 1.f) * 32.f - 0.5f;
    float qy = (gy + 1.f) * 32.f - 0.5f;
    float gx0 = floorf(qx), gy0 = floorf(qy);
    float ax1 = qx - gx0, ay1 = qy - gy0, ax0 = 1.f - ax1, ay0 = 1.f - ay1;
    int cx0 = (int)gx0, cy0 = (int)gy0;
    bool FX0 = (cx0 >= 0 && cx0 < 64), FX1 = (cx0 + 1 >= 0 && cx0 + 1 < 64);
    bool FY0 = (cy0 >= 0 && cy0 < 64), FY1 = (cy0 + 1 >= 0 && cy0 + 1 < 64);
    int fxa = min(max(cx0, 0), 63), fxb = min(max(cx0 + 1, 0), 63);
    int fya = min(max(cy0, 0), 63), fyb = min(max(cy0 + 1, 0), 63);
    float m00 = (FY0 && FX0) ? ay0 * ax0 : 0.f;
    float m01 = (FY0 && FX1) ? ay0 * ax1 : 0.f;
    float m10 = (FY1 && FX0) ? ay1 * ax0 : 0.f;
    float m11 = (FY1 && FX1) ? ay1 * ax1 : 0.f;
    const float* pfb = pf + (size_t)b * 4096 * 64;
    const float* p00 = pfb + ((size_t)fya * 64 + fxa) * 64;
    const float* p01 = pfb + ((size_t)fya * 64 + fxb) * 64;
    const float* p10 = pfb + ((size_t)fyb * 64 + fxa) * 64;
    const float* p11 = pfb + ((size_t)fyb * 64 + fxb) * 64;

    float* xr = xfeat + ((size_t)v * NB + b) * 64;
#pragma unroll
    for (int j = 0; j < 4; j++) {
        int c = ln + 16 * j;
        if (c < CU) {
            float val = m00 * p00[c] + m01 * p01[c] + m10 * p10[c] + m11 * p11[c];
            xr[c] = vis * val + convb[c];
        } else {
            xr[c] = vp[c - CU];
        }
    }
}

// ---- CSR build ----
__global__ void k_count(const int* __restrict__ erow, int* __restrict__ counts) {
    int e = blockIdx.x * 256 + threadIdx.x;
    if (e < NE) atomicAdd(&counts[erow[e]], 1);
}

__global__ void k_scan(const int* __restrict__ counts, int* __restrict__ offs) {
    __shared__ int part[1024];
    int t = threadIdx.x;
    int base = t * 12;
    int local[12];
    int s = 0;
#pragma unroll
    for (int i = 0; i < 12; i++) { local[i] = s; s += counts[base + i]; }
    part[t] = s;
    __syncthreads();
    for (int off = 1; off < 1024; off <<= 1) {
        int v = (t >= off) ? part[t - off] : 0;
        __syncthreads();
        part[t] += v;
        __syncthreads();
    }
    int prefix = part[t] - s;   // exclusive
#pragma unroll
    for (int i = 0; i < 12; i++) offs[base + i] = prefix + local[i];
}

__global__ void k_fill(const int* __restrict__ erow, const int* __restrict__ ecol,
                       const int* __restrict__ offs, int* __restrict__ cursor,
                       int* __restrict__ csr) {
    int e = blockIdx.x * 256 + threadIdx.x;
    if (e >= NE) return;
    int r = erow[e];
    int pos = offs[r] + atomicAdd(&cursor[r], 1);
    csr[pos] = ecol[e];
}

// gather-agg 64-wide over all 8 batches; one wave per dest vertex; fold 1/deg
__global__ void k_agg1(const int* __restrict__ counts, const int* __restrict__ offs,
                       const int* __restrict__ csr, const float* __restrict__ xfeat,
                       float* __restrict__ agg1d) {
    int wid = (blockIdx.x * 256 + threadIdx.x) >> 6;   // vertex
    int l = threadIdx.x & 63;
    if (wid >= NV) return;
    int beg = offs[wid], n = counts[wid];
    float a0x = 0.f, a0y = 0.f, a0z = 0.f, a0w = 0.f;
    float a1x = 0.f, a1y = 0.f, a1z = 0.f, a1w = 0.f;
    for (int j = 0; j < n; j++) {
        int c = csr[beg + j];
        const float4* src = (const float4*)(xfeat + (size_t)c * 512);
        float4 u = src[l];
        float4 w = src[64 + l];
        a0x += u.x; a0y += u.y; a0z += u.z; a0w += u.w;
        a1x += w.x; a1y += w.y; a1z += w.z; a1w += w.w;
    }
    float dinv = 1.f / fmaxf((float)n, 1.f);
    float4* dst = (float4*)(agg1d + (size_t)wid * 512);
    dst[l]      = make_float4(a0x * dinv, a0y * dinv, a0z * dinv, a0w * dinv);
    dst[64 + l] = make_float4(a1x * dinv, a1y * dinv, a1z * dinv, a1w * dinv);
}

// fused MLP: block = 256 threads = 64 rows x 4 quarters (q wave-uniform)
// h = relu(agg1d@W1+b1) -> LDS; y2 = h@W2; dv = h@Wdv (LDS-reduced)
__global__ void k_mlp(const float* __restrict__ agg1d, const float* __restrict__ W1,
                      const float* __restrict__ b1, const float* __restrict__ W2,
                      const float* __restrict__ Wdv, const float* __restrict__ verts,
                      float* __restrict__ y2, float* __restrict__ out) {
    __shared__ float hlds[128][64];   // 32 KB [k][row]
    __shared__ float dvp[4][64][4];   //  4 KB [q][row][j]
    int tid = threadIdx.x;
    int r = tid & 63, q = tid >> 6;   // q wave-uniform
    int row = blockIdx.x * 64 + r;    // row = v*8+b (vertex-major)
    const float4* ar4 = (const float4*)(agg1d + (size_t)row * 64);
    float acc[32];
#pragma unroll
    for (int o = 0; o < 32; o++) acc[o] = 0.f;
    for (int kk = 0; kk < 16; kk++) {
        float4 xv4 = ar4[kk];
        const float* w0 = W1 + (kk * 4 + 0) * 128 + q * 32;
        const float* w1 = W1 + (kk * 4 + 1) * 128 + q * 32;
        const float* w2 = W1 + (kk * 4 + 2) * 128 + q * 32;
        const float* w3 = W1 + (kk * 4 + 3) * 128 + q * 32;
#pragma unroll
        for (int o = 0; o < 32; o++) {
            float t = fmaf(xv4.x, w0[o], acc[o]);
            t = fmaf(xv4.y, w1[o], t);
            t = fmaf(xv4.z, w2[o], t);
            acc[o] = fmaf(xv4.w, w3[o], t);
        }
    }
#pragma unroll
    for (int o = 0; o < 32; o++)
        hlds[q * 32 + o][r] = fmaxf(acc[o] + b1[q * 32 + o], 0.f);
    __syncthreads();

    float y[8];
#pragma unroll
    for (int o = 0; o < 8; o++) y[o] = 0.f;
    for (int k = 0; k < 128; k++) {
        float hv = hlds[k][r];
        const float* w2 = W2 + k * 32 + q * 8;
#pragma unroll
        for (int o = 0; o < 8; o++) y[o] = fmaf(hv, w2[o], y[o]);
    }
    float d0 = 0.f, d1 = 0.f, d2 = 0.f;
    for (int k = q * 32; k < q * 32 + 32; k++) {
        float hv = hlds[k][r];
        d0 = fmaf(hv, Wdv[k * 3 + 0], d0);
        d1 = fmaf(hv, Wdv[k * 3 + 1], d1);
        d2 = fmaf(hv, Wdv[k * 3 + 2], d2);
    }
    dvp[q][r][0] = d0; dvp[q][r][1] = d1; dvp[q][r][2] = d2;

    float* yr = y2 + (size_t)row * 32 + q * 8;
#pragma unroll
    for (int o = 0; o < 8; o++) yr[o] = y[o];
    __syncthreads();

    if (q == 0) {
        float e0 = dvp[0][r][0] + dvp[1][r][0] + dvp[2][r][0] + dvp[3][r][0];
        float e1 = dvp[0][r][1] + dvp[1][r][1] + dvp[2][r][1] + dvp[3][r][1];
        float e2 = dvp[0][r][2] + dvp[1][r][2] + dvp[2][r][2] + dvp[3][r][2];
        int v = row >> 3, b = row & 7;
        const float* vp = verts + ((size_t)b * NV + v) * 3;
        float* orow = out + ((size_t)b * NV + v) * 38;
        orow[32] = (vp[0] + e0) * 1000.f;
        orow[33] = (vp[1] + e1) * 1000.f;
        orow[34] = (vp[2] + e2) * 1000.f;
        orow[35] = e0 * 1000.f;
        orow[36] = e1 * 1000.f;
        orow[37] = e2 * 1000.f;
    }
}

// gather-agg over y2 (32-wide x 8 batches = 256 floats/vertex); write out[0..31]
__global__ void k_agg2(const int* __restrict__ counts, const int* __restrict__ offs,
                       const int* __restrict__ csr, const float* __restrict__ y2,
                       float* __restrict__ out) {
    int wid = (blockIdx.x * 256 + threadIdx.x) >> 6;   // vertex
    int l = threadIdx.x & 63;
    if (wid >= NV) return;
    int beg = offs[wid], n = counts[wid];
    float ax = 0.f, ay = 0.f, az = 0.f, aw = 0.f;
    for (int j = 0; j < n; j++) {
        int c = csr[beg + j];
        const float4* src = (const float4*)(y2 + (size_t)c * 256);
        float4 u = src[l];
        ax += u.x; ay += u.y; az += u.z; aw += u.w;
    }
    float dinv = 1.f / fmaxf((float)n, 1.f);
    int b = l >> 3, o = (l & 7) * 4;
    float* orow = out + ((size_t)b * NV + wid) * 38 + o;
    orow[0] = ax * dinv;
    orow[1] = ay * dinv;
    orow[2] = az * dinv;
    orow[3] = aw * dinv;
}

extern "C" void kernel_launch(void* const* d_in, const int* in_sizes, int n_in,
                              void* d_out, int out_size, void* d_ws, size_t ws_size,
                              hipStream_t stream) {
    const float* fm  = (const float*)d_in[0];
    const float* dm  = (const float*)d_in[1];
    const float* vt  = (const float*)d_in[2];
    const float* fz  = (const float*)d_in[3];
    const float* cz  = (const float*)d_in[4];
    const float* cw  = (const float*)d_in[5];
    const float* cb  = (const float*)d_in[6];
    const float* W1  = (const float*)d_in[7];
    const float* b1  = (const float*)d_in[8];
    const float* W2  = (const float*)d_in[9];
    const float* Wdv = (const float*)d_in[10];
    const int* erow  = (const int*)d_in[11];
    const int* ecol  = (const int*)d_in[12];
    float* out = (float*)d_out;

    float* ws    = (float*)d_ws;
    float* pf    = ws;                   // 2097152
    float* xfeat = pf + 2097152;         // 6291456
    float* agg1d = xfeat + 6291456;      // 6291456
    float* y2    = agg1d + 6291456;      // 3145728
    float* cwT   = y2 + 3145728;         // 24576
    int* counts  = (int*)(cwT + 24576);  // 12288
    int* offs    = counts + 12288;       // 12288
    int* cursor  = offs + 12288;         // 12288
    int* csr     = cursor + 12288;       // 147456

    hipMemsetAsync(counts, 0, 12288 * sizeof(int), stream);
    hipMemsetAsync(cursor, 0, 12288 * sizeof(int), stream);

    k_wt<<<96, 256, 0, stream>>>(cw, cwT);
    k_conv<<<512, 128, 0, stream>>>(fm, cwT, pf);
    k_sample<<<6144, 256, 0, stream>>>(dm, pf, vt, fz, cz, cb, xfeat);
    k_count<<<576, 256, 0, stream>>>(erow, counts);
    k_scan<<<1, 1024, 0, stream>>>(counts, offs);
    k_fill<<<576, 256, 0, stream>>>(erow, ecol, offs, cursor, csr);
    k_agg1<<<3072, 256, 0, stream>>>(counts, offs, csr, xfeat, agg1d);
    k_mlp<<<1536, 256, 0, stream>>>(agg1d, W1, b1, W2, Wdv, vt, y2, out);
    k_agg2<<<3072, 256, 0, stream>>>(counts, offs, csr, y2, out);
}

// Round 4
// 360.008 us; speedup vs baseline: 3.2216x; 1.1691x over previous
//
#include <hip/hip_runtime.h>

#define NB 8
#define NV 12288
#define NE 147456
#define CFM 384
#define CU 61
#define FEPS 0.005f

// ---------- ws layout ----------
// pf    : NB*4096*64 f  = 2097152   (conv-projected feature map, [b][p][64])
// xfeat : NV*NB*64 f    = 6291456   (vertex-major GNN input)
// agg1d : NV*NB*64 f    = 6291456   (gathered+divided)
// y2    : NV*NB*32 f    = 3145728   (h @ W2, vertex-major)
// cwT   : 384*64 f      = 24576
// counts: NV int, offs: NV int, cursor: NV int, csr: NE int

// transpose conv_w (61,384) -> cwT (384,64), zero-pad o>=61
__global__ void k_wt(const float* __restrict__ cw, float* __restrict__ cwT) {
    int idx = blockIdx.x * 256 + threadIdx.x;
    if (idx >= CFM * 64) return;
    int c = idx >> 6, o = idx & 63;
    cwT[idx] = (o < CU) ? cw[o * CFM + c] : 0.f;
}

// pf[b][p][o] = sum_c cwT[c][o] * fm[b][c][p]
// block = 256 threads = 64 positions x 4 output-groups of 16 (og wave-uniform)
// fm staged through LDS tile [32 c][64 p]; acc[16] per thread -> no spill
__global__ void k_conv(const float* __restrict__ fm, const float* __restrict__ cwT,
                       float* __restrict__ pf) {
    __shared__ float ftile[32][64];   // 8 KB
    int tid = threadIdx.x;
    int lane = tid & 63;              // position within tile
    int og = tid >> 6;                // output group (wave-uniform)
    int idx0 = blockIdx.x * 64;       // 512 blocks cover NB*4096 positions
    int b = idx0 >> 12, p0 = idx0 & 4095;
    const float* fb = fm + (size_t)b * CFM * 4096 + p0;
    float acc[16];
#pragma unroll
    for (int o = 0; o < 16; o++) acc[o] = 0.f;
    for (int cc = 0; cc < CFM; cc += 32) {
        // stage 32x64 fm tile: 2048 elems, 8 per thread, coalesced
#pragma unroll
        for (int i = 0; i < 8; i++) {
            int lin = tid + 256 * i;
            int c = lin >> 6, pp = lin & 63;
            ftile[c][pp] = fb[(size_t)(cc + c) * 4096 + pp];
        }
        __syncthreads();
#pragma unroll 8
        for (int c = 0; c < 32; c++) {
            float fv = ftile[c][lane];
            const float* w = cwT + (cc + c) * 64 + og * 16;  // uniform -> scalar
#pragma unroll
            for (int o = 0; o < 16; o++) acc[o] = fmaf(fv, w[o], acc[o]);
        }
        __syncthreads();
    }
    // write 16 outputs (padding lanes 61..63 are never read downstream)
    float4* outp = (float4*)(pf + (size_t)(idx0 + lane) * 64 + og * 16);
#pragma unroll
    for (int o4 = 0; o4 < 4; o4++)
        outp[o4] = make_float4(acc[o4 * 4], acc[o4 * 4 + 1], acc[o4 * 4 + 2], acc[o4 * 4 + 3]);
}

// per-vertex projection + depth visibility + feature bilinear -> xfeat[v][b][64]
__global__ void k_sample(const float* __restrict__ depth, const float* __restrict__ pf,
                         const float* __restrict__ verts, const float* __restrict__ fz,
                         const float* __restrict__ cz, const float* __restrict__ convb,
                         float* __restrict__ xfeat) {
    int t = blockIdx.x * 256 + threadIdx.x;
    int gid = t >> 4;                 // b*NV+v
    int ln = t & 15;
    int b = gid / NV;
    int v = gid - b * NV;
    const float* vp = verts + (size_t)gid * 3;
    float vx = vp[0], vy = vp[1], vz = vp[2];
    float fzb = fz[b], czb = cz[2 * b];
    float gx = fzb * vx + czb;
    float gy = fzb * vy + czb;
    float gz = fzb * (vz + 100.f);

    // depth bilinear (128x128), zero padding
    float px = (gx + 1.f) * 64.f - 0.5f;
    float py = (gy + 1.f) * 64.f - 0.5f;
    float fx0 = floorf(px), fy0 = floorf(py);
    float wx1 = px - fx0, wy1 = py - fy0, wx0 = 1.f - wx1, wy0 = 1.f - wy1;
    int x0 = (int)fx0, y0 = (int)fy0;
    const float* dmb = depth + (size_t)b * 128 * 128;
    float d00 = 0.f, d01 = 0.f, d10 = 0.f, d11 = 0.f;
    bool X0 = (x0 >= 0 && x0 < 128), X1 = (x0 + 1 >= 0 && x0 + 1 < 128);
    bool Y0 = (y0 >= 0 && y0 < 128), Y1 = (y0 + 1 >= 0 && y0 + 1 < 128);
    int xa = min(max(x0, 0), 127), xb = min(max(x0 + 1, 0), 127);
    int ya = min(max(y0, 0), 127), yb = min(max(y0 + 1, 0), 127);
    if (Y0 && X0) d00 = dmb[ya * 128 + xa];
    if (Y0 && X1) d01 = dmb[ya * 128 + xb];
    if (Y1 && X0) d10 = dmb[yb * 128 + xa];
    if (Y1 && X1) d11 = dmb[yb * 128 + xb];
    float sd = d00 * wy0 * wx0 + d01 * wy0 * wx1 + d10 * wy1 * wx0 + d11 * wy1 * wx1;
    float vis = (fabsf(sd - gz) < FEPS) ? 1.f : 0.f;

    // feature bilinear (64x64) on pf
    float qx = (gx + 1.f) * 32.f - 0.5f;
    float qy = (gy + 1.f) * 32.f - 0.5f;
    float gx0 = floorf(qx), gy0 = floorf(qy);
    float ax1 = qx - gx0, ay1 = qy - gy0, ax0 = 1.f - ax1, ay0 = 1.f - ay1;
    int cx0 = (int)gx0, cy0 = (int)gy0;
    bool FX0 = (cx0 >= 0 && cx0 < 64), FX1 = (cx0 + 1 >= 0 && cx0 + 1 < 64);
    bool FY0 = (cy0 >= 0 && cy0 < 64), FY1 = (cy0 + 1 >= 0 && cy0 + 1 < 64);
    int fxa = min(max(cx0, 0), 63), fxb = min(max(cx0 + 1, 0), 63);
    int fya = min(max(cy0, 0), 63), fyb = min(max(cy0 + 1, 0), 63);
    float m00 = (FY0 && FX0) ? ay0 * ax0 : 0.f;
    float m01 = (FY0 && FX1) ? ay0 * ax1 : 0.f;
    float m10 = (FY1 && FX0) ? ay1 * ax0 : 0.f;
    float m11 = (FY1 && FX1) ? ay1 * ax1 : 0.f;
    const float* pfb = pf + (size_t)b * 4096 * 64;
    const float* p00 = pfb + ((size_t)fya * 64 + fxa) * 64;
    const float* p01 = pfb + ((size_t)fya * 64 + fxb) * 64;
    const float* p10 = pfb + ((size_t)fyb * 64 + fxa) * 64;
    const float* p11 = pfb + ((size_t)fyb * 64 + fxb) * 64;

    float* xr = xfeat + ((size_t)v * NB + b) * 64;
#pragma unroll
    for (int j = 0; j < 4; j++) {
        int c = ln + 16 * j;
        if (c < CU) {
            float val = m00 * p00[c] + m01 * p01[c] + m10 * p10[c] + m11 * p11[c];
            xr[c] = vis * val + convb[c];
        } else {
            xr[c] = vp[c - CU];
        }
    }
}

// ---- CSR build ----
__global__ void k_count(const int* __restrict__ erow, int* __restrict__ counts) {
    int e = blockIdx.x * 256 + threadIdx.x;
    if (e < NE) atomicAdd(&counts[erow[e]], 1);
}

__global__ void k_scan(const int* __restrict__ counts, int* __restrict__ offs) {
    __shared__ int part[1024];
    int t = threadIdx.x;
    int base = t * 12;
    int local[12];
    int s = 0;
#pragma unroll
    for (int i = 0; i < 12; i++) { local[i] = s; s += counts[base + i]; }
    part[t] = s;
    __syncthreads();
    for (int off = 1; off < 1024; off <<= 1) {
        int v = (t >= off) ? part[t - off] : 0;
        __syncthreads();
        part[t] += v;
        __syncthreads();
    }
    int prefix = part[t] - s;   // exclusive
#pragma unroll
    for (int i = 0; i < 12; i++) offs[base + i] = prefix + local[i];
}

__global__ void k_fill(const int* __restrict__ erow, const int* __restrict__ ecol,
                       const int* __restrict__ offs, int* __restrict__ cursor,
                       int* __restrict__ csr) {
    int e = blockIdx.x * 256 + threadIdx.x;
    if (e >= NE) return;
    int r = erow[e];
    int pos = offs[r] + atomicAdd(&cursor[r], 1);
    csr[pos] = ecol[e];
}

// gather-agg 64-wide over all 8 batches; one wave per dest vertex; fold 1/deg
__global__ void k_agg1(const int* __restrict__ counts, const int* __restrict__ offs,
                       const int* __restrict__ csr, const float* __restrict__ xfeat,
                       float* __restrict__ agg1d) {
    int wid = (blockIdx.x * 256 + threadIdx.x) >> 6;   // vertex
    int l = threadIdx.x & 63;
    if (wid >= NV) return;
    int beg = offs[wid], n = counts[wid];
    float a0x = 0.f, a0y = 0.f, a0z = 0.f, a0w = 0.f;
    float a1x = 0.f, a1y = 0.f, a1z = 0.f, a1w = 0.f;
    for (int j = 0; j < n; j++) {
        int c = csr[beg + j];
        const float4* src = (const float4*)(xfeat + (size_t)c * 512);
        float4 u = src[l];
        float4 w = src[64 + l];
        a0x += u.x; a0y += u.y; a0z += u.z; a0w += u.w;
        a1x += w.x; a1y += w.y; a1z += w.z; a1w += w.w;
    }
    float dinv = 1.f / fmaxf((float)n, 1.f);
    float4* dst = (float4*)(agg1d + (size_t)wid * 512);
    dst[l]      = make_float4(a0x * dinv, a0y * dinv, a0z * dinv, a0w * dinv);
    dst[64 + l] = make_float4(a1x * dinv, a1y * dinv, a1z * dinv, a1w * dinv);
}

// fused MLP: block = 256 threads = 64 rows x 4 quarters (q wave-uniform)
// h = relu(agg1d@W1+b1) -> LDS; y2 = h@W2; dv = h@Wdv (LDS-reduced)
__global__ void k_mlp(const float* __restrict__ agg1d, const float* __restrict__ W1,
                      const float* __restrict__ b1, const float* __restrict__ W2,
                      const float* __restrict__ Wdv, const float* __restrict__ verts,
                      float* __restrict__ y2, float* __restrict__ out) {
    __shared__ float hlds[128][64];   // 32 KB [k][row]
    __shared__ float dvp[4][64][4];   //  4 KB [q][row][j]
    int tid = threadIdx.x;
    int r = tid & 63, q = tid >> 6;   // q wave-uniform
    int row = blockIdx.x * 64 + r;    // row = v*8+b (vertex-major)
    const float4* ar4 = (const float4*)(agg1d + (size_t)row * 64);
    float acc[32];
#pragma unroll
    for (int o = 0; o < 32; o++) acc[o] = 0.f;
    for (int kk = 0; kk < 16; kk++) {
        float4 xv4 = ar4[kk];
        const float* w0 = W1 + (kk * 4 + 0) * 128 + q * 32;
        const float* w1 = W1 + (kk * 4 + 1) * 128 + q * 32;
        const float* w2 = W1 + (kk * 4 + 2) * 128 + q * 32;
        const float* w3 = W1 + (kk * 4 + 3) * 128 + q * 32;
#pragma unroll
        for (int o = 0; o < 32; o++) {
            float t = fmaf(xv4.x, w0[o], acc[o]);
            t = fmaf(xv4.y, w1[o], t);
            t = fmaf(xv4.z, w2[o], t);
            acc[o] = fmaf(xv4.w, w3[o], t);
        }
    }
#pragma unroll
    for (int o = 0; o < 32; o++)
        hlds[q * 32 + o][r] = fmaxf(acc[o] + b1[q * 32 + o], 0.f);
    __syncthreads();

    float y[8];
#pragma unroll
    for (int o = 0; o < 8; o++) y[o] = 0.f;
    for (int k = 0; k < 128; k++) {
        float hv = hlds[k][r];
        const float* w2 = W2 + k * 32 + q * 8;
#pragma unroll
        for (int o = 0; o < 8; o++) y[o] = fmaf(hv, w2[o], y[o]);
    }
    float d0 = 0.f, d1 = 0.f, d2 = 0.f;
    for (int k = q * 32; k < q * 32 + 32; k++) {
        float hv = hlds[k][r];
        d0 = fmaf(hv, Wdv[k * 3 + 0], d0);
        d1 = fmaf(hv, Wdv[k * 3 + 1], d1);
        d2 = fmaf(hv, Wdv[k * 3 + 2], d2);
    }
    dvp[q][r][0] = d0; dvp[q][r][1] = d1; dvp[q][r][2] = d2;

    float* yr = y2 + (size_t)row * 32 + q * 8;
#pragma unroll
    for (int o = 0; o < 8; o++) yr[o] = y[o];
    __syncthreads();

    if (q == 0) {
        float e0 = dvp[0][r][0] + dvp[1][r][0] + dvp[2][r][0] + dvp[3][r][0];
        float e1 = dvp[0][r][1] + dvp[1][r][1] + dvp[2][r][1] + dvp[3][r][1];
        float e2 = dvp[0][r][2] + dvp[1][r][2] + dvp[2][r][2] + dvp[3][r][2];
        int v = row >> 3, b = row & 7;
        const float* vp = verts + ((size_t)b * NV + v) * 3;
        float* orow = out + ((size_t)b * NV + v) * 38;
        orow[32] = (vp[0] + e0) * 1000.f;
        orow[33] = (vp[1] + e1) * 1000.f;
        orow[34] = (vp[2] + e2) * 1000.f;
        orow[35] = e0 * 1000.f;
        orow[36] = e1 * 1000.f;
        orow[37] = e2 * 1000.f;
    }
}

// gather-agg over y2 (32-wide x 8 batches = 256 floats/vertex); write out[0..31]
__global__ void k_agg2(const int* __restrict__ counts, const int* __restrict__ offs,
                       const int* __restrict__ csr, const float* __restrict__ y2,
                       float* __restrict__ out) {
    int wid = (blockIdx.x * 256 + threadIdx.x) >> 6;   // vertex
    int l = threadIdx.x & 63;
    if (wid >= NV) return;
    int beg = offs[wid], n = counts[wid];
    float ax = 0.f, ay = 0.f, az = 0.f, aw = 0.f;
    for (int j = 0; j < n; j++) {
        int c = csr[beg + j];
        const float4* src = (const float4*)(y2 + (size_t)c * 256);
        float4 u = src[l];
        ax += u.x; ay += u.y; az += u.z; aw += u.w;
    }
    float dinv = 1.f / fmaxf((float)n, 1.f);
    int b = l >> 3, o = (l & 7) * 4;
    float* orow = out + ((size_t)b * NV + wid) * 38 + o;
    orow[0] = ax * dinv;
    orow[1] = ay * dinv;
    orow[2] = az * dinv;
    orow[3] = aw * dinv;
}

extern "C" void kernel_launch(void* const* d_in, const int* in_sizes, int n_in,
                              void* d_out, int out_size, void* d_ws, size_t ws_size,
                              hipStream_t stream) {
    const float* fm  = (const float*)d_in[0];
    const float* dm  = (const float*)d_in[1];
    const float* vt  = (const float*)d_in[2];
    const float* fz  = (const float*)d_in[3];
    const float* cz  = (const float*)d_in[4];
    const float* cw  = (const float*)d_in[5];
    const float* cb  = (const float*)d_in[6];
    const float* W1  = (const float*)d_in[7];
    const float* b1  = (const float*)d_in[8];
    const float* W2  = (const float*)d_in[9];
    const float* Wdv = (const float*)d_in[10];
    const int* erow  = (const int*)d_in[11];
    const int* ecol  = (const int*)d_in[12];
    float* out = (float*)d_out;

    float* ws    = (float*)d_ws;
    float* pf    = ws;                   // 2097152
    float* xfeat = pf + 2097152;         // 6291456
    float* agg1d = xfeat + 6291456;      // 6291456
    float* y2    = agg1d + 6291456;      // 3145728
    float* cwT   = y2 + 3145728;         // 24576
    int* counts  = (int*)(cwT + 24576);  // 12288
    int* offs    = counts + 12288;       // 12288
    int* cursor  = offs + 12288;         // 12288
    int* csr     = cursor + 12288;       // 147456

    hipMemsetAsync(counts, 0, 12288 * sizeof(int), stream);
    hipMemsetAsync(cursor, 0, 12288 * sizeof(int), stream);

    k_wt<<<96, 256, 0, stream>>>(cw, cwT);
    k_conv<<<512, 256, 0, stream>>>(fm, cwT, pf);
    k_sample<<<6144, 256, 0, stream>>>(dm, pf, vt, fz, cz, cb, xfeat);
    k_count<<<576, 256, 0, stream>>>(erow, counts);
    k_scan<<<1, 1024, 0, stream>>>(counts, offs);
    k_fill<<<576, 256, 0, stream>>>(erow, ecol, offs, cursor, csr);
    k_agg1<<<3072, 256, 0, stream>>>(counts, offs, csr, xfeat, agg1d);
    k_mlp<<<1536, 256, 0, stream>>>(agg1d, W1, b1, W2, Wdv, vt, y2, out);
    k_agg2<<<3072, 256, 0, stream>>>(counts, offs, csr, y2, out);
}

// Round 5
// 261.373 us; speedup vs baseline: 4.4374x; 1.3774x over previous
//
#include <hip/hip_runtime.h>

#define NB 8
#define NV 12288
#define NE 147456
#define CFM 384
#define CU 61
#define FEPS 0.005f

// ---------- ws layout ----------
// pf    : NB*4096*64 f  = 2097152   (conv-projected feature map, [b][p][64])
// xfeat : NV*NB*64 f    = 6291456   (vertex-major GNN input)
// agg1d : NV*NB*64 f    = 6291456   (gathered+divided)
// y2    : NV*NB*32 f    = 3145728   (h @ W2, vertex-major)
// cwT   : 384*64 f      = 24576
// counts: NV int, offs: NV int, cursor: NV int, csr: NE int

// transpose conv_w (61,384) -> cwT (384,64), zero-pad o>=61
__global__ void k_wt(const float* __restrict__ cw, float* __restrict__ cwT) {
    int idx = blockIdx.x * 256 + threadIdx.x;
    if (idx >= CFM * 64) return;
    int c = idx >> 6, o = idx & 63;
    cwT[idx] = (o < CU) ? cw[o * CFM + c] : 0.f;
}

// pf[b][p][o] = sum_c cwT[c][o] * fm[b][c][p]
// block = 256 threads = 64 positions x 4 output-groups of 16 (og wave-uniform)
__global__ void k_conv(const float* __restrict__ fm, const float* __restrict__ cwT,
                       float* __restrict__ pf) {
    __shared__ float ftile[32][64];   // 8 KB
    int tid = threadIdx.x;
    int lane = tid & 63;
    int og = tid >> 6;
    int idx0 = blockIdx.x * 64;
    int b = idx0 >> 12, p0 = idx0 & 4095;
    const float* fb = fm + (size_t)b * CFM * 4096 + p0;
    float acc[16];
#pragma unroll
    for (int o = 0; o < 16; o++) acc[o] = 0.f;
    for (int cc = 0; cc < CFM; cc += 32) {
#pragma unroll
        for (int i = 0; i < 8; i++) {
            int lin = tid + 256 * i;
            int c = lin >> 6, pp = lin & 63;
            ftile[c][pp] = fb[(size_t)(cc + c) * 4096 + pp];
        }
        __syncthreads();
#pragma unroll 8
        for (int c = 0; c < 32; c++) {
            float fv = ftile[c][lane];
            const float* w = cwT + (cc + c) * 64 + og * 16;
#pragma unroll
            for (int o = 0; o < 16; o++) acc[o] = fmaf(fv, w[o], acc[o]);
        }
        __syncthreads();
    }
    float4* outp = (float4*)(pf + (size_t)(idx0 + lane) * 64 + og * 16);
#pragma unroll
    for (int o4 = 0; o4 < 4; o4++)
        outp[o4] = make_float4(acc[o4 * 4], acc[o4 * 4 + 1], acc[o4 * 4 + 2], acc[o4 * 4 + 3]);
}

// per-vertex projection + depth visibility + feature bilinear -> xfeat[v][b][64]
__global__ void k_sample(const float* __restrict__ depth, const float* __restrict__ pf,
                         const float* __restrict__ verts, const float* __restrict__ fz,
                         const float* __restrict__ cz, const float* __restrict__ convb,
                         float* __restrict__ xfeat) {
    int t = blockIdx.x * 256 + threadIdx.x;
    int gid = t >> 4;                 // b*NV+v
    int ln = t & 15;
    int b = gid / NV;
    int v = gid - b * NV;
    const float* vp = verts + (size_t)gid * 3;
    float vx = vp[0], vy = vp[1], vz = vp[2];
    float fzb = fz[b], czb = cz[2 * b];
    float gx = fzb * vx + czb;
    float gy = fzb * vy + czb;
    float gz = fzb * (vz + 100.f);

    float px = (gx + 1.f) * 64.f - 0.5f;
    float py = (gy + 1.f) * 64.f - 0.5f;
    float fx0 = floorf(px), fy0 = floorf(py);
    float wx1 = px - fx0, wy1 = py - fy0, wx0 = 1.f - wx1, wy0 = 1.f - wy1;
    int x0 = (int)fx0, y0 = (int)fy0;
    const float* dmb = depth + (size_t)b * 128 * 128;
    float d00 = 0.f, d01 = 0.f, d10 = 0.f, d11 = 0.f;
    bool X0 = (x0 >= 0 && x0 < 128), X1 = (x0 + 1 >= 0 && x0 + 1 < 128);
    bool Y0 = (y0 >= 0 && y0 < 128), Y1 = (y0 + 1 >= 0 && y0 + 1 < 128);
    int xa = min(max(x0, 0), 127), xb = min(max(x0 + 1, 0), 127);
    int ya = min(max(y0, 0), 127), yb = min(max(y0 + 1, 0), 127);
    if (Y0 && X0) d00 = dmb[ya * 128 + xa];
    if (Y0 && X1) d01 = dmb[ya * 128 + xb];
    if (Y1 && X0) d10 = dmb[yb * 128 + xa];
    if (Y1 && X1) d11 = dmb[yb * 128 + xb];
    float sd = d00 * wy0 * wx0 + d01 * wy0 * wx1 + d10 * wy1 * wx0 + d11 * wy1 * wx1;
    float vis = (fabsf(sd - gz) < FEPS) ? 1.f : 0.f;

    float qx = (gx + 1.f) * 32.f - 0.5f;
    float qy = (gy + 1.f) * 32.f - 0.5f;
    float gx0 = floorf(qx), gy0 = floorf(qy);
    float ax1 = qx - gx0, ay1 = qy - gy0, ax0 = 1.f - ax1, ay0 = 1.f - ay1;
    int cx0 = (int)gx0, cy0 = (int)gy0;
    bool FX0 = (cx0 >= 0 && cx0 < 64), FX1 = (cx0 + 1 >= 0 && cx0 + 1 < 64);
    bool FY0 = (cy0 >= 0 && cy0 < 64), FY1 = (cy0 + 1 >= 0 && cy0 + 1 < 64);
    int fxa = min(max(cx0, 0), 63), fxb = min(max(cx0 + 1, 0), 63);
    int fya = min(max(cy0, 0), 63), fyb = min(max(cy0 + 1, 0), 63);
    float m00 = (FY0 && FX0) ? ay0 * ax0 : 0.f;
    float m01 = (FY0 && FX1) ? ay0 * ax1 : 0.f;
    float m10 = (FY1 && FX0) ? ay1 * ax0 : 0.f;
    float m11 = (FY1 && FX1) ? ay1 * ax1 : 0.f;
    const float* pfb = pf + (size_t)b * 4096 * 64;
    const float* p00 = pfb + ((size_t)fya * 64 + fxa) * 64;
    const float* p01 = pfb + ((size_t)fya * 64 + fxb) * 64;
    const float* p10 = pfb + ((size_t)fyb * 64 + fxa) * 64;
    const float* p11 = pfb + ((size_t)fyb * 64 + fxb) * 64;

    float* xr = xfeat + ((size_t)v * NB + b) * 64;
#pragma unroll
    for (int j = 0; j < 4; j++) {
        int c = ln + 16 * j;
        if (c < CU) {
            float val = m00 * p00[c] + m01 * p01[c] + m10 * p10[c] + m11 * p11[c];
            xr[c] = vis * val + convb[c];
        } else {
            xr[c] = vp[c - CU];
        }
    }
}

// ---- CSR build ----
__global__ void k_count(const int* __restrict__ erow, int* __restrict__ counts) {
    int e = blockIdx.x * 256 + threadIdx.x;
    if (e < NE) atomicAdd(&counts[erow[e]], 1);
}

__global__ void k_scan(const int* __restrict__ counts, int* __restrict__ offs) {
    __shared__ int part[1024];
    int t = threadIdx.x;
    int base = t * 12;
    int local[12];
    int s = 0;
#pragma unroll
    for (int i = 0; i < 12; i++) { local[i] = s; s += counts[base + i]; }
    part[t] = s;
    __syncthreads();
    for (int off = 1; off < 1024; off <<= 1) {
        int v = (t >= off) ? part[t - off] : 0;
        __syncthreads();
        part[t] += v;
        __syncthreads();
    }
    int prefix = part[t] - s;   // exclusive
#pragma unroll
    for (int i = 0; i < 12; i++) offs[base + i] = prefix + local[i];
}

__global__ void k_fill(const int* __restrict__ erow, const int* __restrict__ ecol,
                       const int* __restrict__ offs, int* __restrict__ cursor,
                       int* __restrict__ csr) {
    int e = blockIdx.x * 256 + threadIdx.x;
    if (e >= NE) return;
    int r = erow[e];
    int pos = offs[r] + atomicAdd(&cursor[r], 1);
    csr[pos] = ecol[e];
}

// gather-agg 64-wide over all 8 batches; one wave per dest vertex; fold 1/deg
__global__ void k_agg1(const int* __restrict__ counts, const int* __restrict__ offs,
                       const int* __restrict__ csr, const float* __restrict__ xfeat,
                       float* __restrict__ agg1d) {
    int wid = (blockIdx.x * 256 + threadIdx.x) >> 6;   // vertex
    int l = threadIdx.x & 63;
    if (wid >= NV) return;
    int beg = offs[wid], n = counts[wid];
    float a0x = 0.f, a0y = 0.f, a0z = 0.f, a0w = 0.f;
    float a1x = 0.f, a1y = 0.f, a1z = 0.f, a1w = 0.f;
    for (int j = 0; j < n; j++) {
        int c = csr[beg + j];
        const float4* src = (const float4*)(xfeat + (size_t)c * 512);
        float4 u = src[l];
        float4 w = src[64 + l];
        a0x += u.x; a0y += u.y; a0z += u.z; a0w += u.w;
        a1x += w.x; a1y += w.y; a1z += w.z; a1w += w.w;
    }
    float dinv = 1.f / fmaxf((float)n, 1.f);
    float4* dst = (float4*)(agg1d + (size_t)wid * 512);
    dst[l]      = make_float4(a0x * dinv, a0y * dinv, a0z * dinv, a0w * dinv);
    dst[64 + l] = make_float4(a1x * dinv, a1y * dinv, a1z * dinv, a1w * dinv);
}

// fused MLP, register-tiled. Block=256, M-tile=64 rows (row = v*8+b).
// Phase1: xT[64k][64r] + W1[64k][128n] in LDS; thread = 4 rows x 8 cols.
// Phase2: h -> hlds[128k][68pad]; w2e[128k][36] (W2|Wdv|pad); thread = 4 rows x 3 cols.
__global__ __launch_bounds__(256) void k_mlp(
        const float* __restrict__ agg1d, const float* __restrict__ W1,
        const float* __restrict__ b1, const float* __restrict__ W2,
        const float* __restrict__ Wdv, const float* __restrict__ verts,
        float* __restrict__ y2, float* __restrict__ out) {
    __shared__ float lds[13440];      // 53760 B
    float* xT   = lds;                // [64][64]   = 4096 f
    float* w1s  = lds + 4096;         // [64][128]  = 8192 f
    float* hlds = lds;                // [128][68]  = 8704 f (phase 2)
    float* w2e  = lds + 8704;         // [128][36]  = 4608 f (phase 2)
    float* b1s  = lds + 13312;        // [128]

    int tid = threadIdx.x;
    int r = tid & 63, q = tid >> 6;
    int base = blockIdx.x * 64;

    if (tid < 128) b1s[tid] = b1[tid];
    // stage xT (transpose of 64 agg1d rows)
    {
        const float4* arow = (const float4*)(agg1d + (size_t)(base + r) * 64 + q * 16);
#pragma unroll
        for (int i = 0; i < 4; i++) {
            float4 u = arow[i];
            int k0 = q * 16 + i * 4;
            xT[(k0 + 0) * 64 + r] = u.x;
            xT[(k0 + 1) * 64 + r] = u.y;
            xT[(k0 + 2) * 64 + r] = u.z;
            xT[(k0 + 3) * 64 + r] = u.w;
        }
    }
    // stage W1 (64x128, already k-major)
    {
        const float4* wsrc = (const float4*)W1;
        float4* wdst = (float4*)w1s;
#pragma unroll
        for (int i = 0; i < 8; i++) {
            int idx = tid + 256 * i;
            wdst[idx] = wsrc[idx];
        }
    }
    __syncthreads();

    // ---- GEMM1: h = relu(x @ W1 + b1)
    int rg = tid & 15, cg = tid >> 4;
    int r0 = rg * 4, c0 = cg * 8;
    float acc[4][8];
#pragma unroll
    for (int i = 0; i < 4; i++)
#pragma unroll
        for (int j = 0; j < 8; j++) acc[i][j] = 0.f;
#pragma unroll 4
    for (int k = 0; k < 64; k++) {
        float4 xv = *(const float4*)(xT + k * 64 + r0);
        float4 wa = *(const float4*)(w1s + k * 128 + c0);
        float4 wb = *(const float4*)(w1s + k * 128 + c0 + 4);
        float xr_[4] = {xv.x, xv.y, xv.z, xv.w};
        float wr_[8] = {wa.x, wa.y, wa.z, wa.w, wb.x, wb.y, wb.z, wb.w};
#pragma unroll
        for (int i = 0; i < 4; i++)
#pragma unroll
            for (int j = 0; j < 8; j++)
                acc[i][j] = fmaf(xr_[i], wr_[j], acc[i][j]);
    }
    float bv[8];
#pragma unroll
    for (int j = 0; j < 8; j++) bv[j] = b1s[c0 + j];
    __syncthreads();   // done reading xT/w1s

    // write h (relu) to hlds[n][row]; stage w2e
#pragma unroll
    for (int j = 0; j < 8; j++)
#pragma unroll
        for (int i = 0; i < 4; i++)
            hlds[(c0 + j) * 68 + r0 + i] = fmaxf(acc[i][j] + bv[j], 0.f);
#pragma unroll
    for (int i = 0; i < 18; i++) {
        int idx = tid + 256 * i;
        int k = idx / 36, c = idx - k * 36;
        float val = (c < 32) ? W2[k * 32 + c] : ((c < 35) ? Wdv[k * 3 + (c - 32)] : 0.f);
        w2e[idx] = val;
    }
    __syncthreads();

    // ---- GEMM2: y2 = h @ W2 (cols 0..31), dv = h @ Wdv (cols 32..34)
    int cg2 = tid >> 4;               // 0..15; active < 12
    int c2 = cg2 * 3;
    if (cg2 < 12) {
        float acc2[4][3];
#pragma unroll
        for (int i = 0; i < 4; i++)
#pragma unroll
            for (int j = 0; j < 3; j++) acc2[i][j] = 0.f;
#pragma unroll 4
        for (int k = 0; k < 128; k++) {
            float4 hv = *(const float4*)(hlds + k * 68 + r0);
            float hr_[4] = {hv.x, hv.y, hv.z, hv.w};
            float w0 = w2e[k * 36 + c2];
            float w1v = w2e[k * 36 + c2 + 1];
            float w2v = w2e[k * 36 + c2 + 2];
#pragma unroll
            for (int i = 0; i < 4; i++) {
                acc2[i][0] = fmaf(hr_[i], w0, acc2[i][0]);
                acc2[i][1] = fmaf(hr_[i], w1v, acc2[i][1]);
                acc2[i][2] = fmaf(hr_[i], w2v, acc2[i][2]);
            }
        }
#pragma unroll
        for (int i = 0; i < 4; i++) {
            int row = base + r0 + i;
#pragma unroll
            for (int j = 0; j < 3; j++) {
                int c = c2 + j;
                if (c < 32) {
                    y2[(size_t)row * 32 + c] = acc2[i][j];
                } else if (c < 35) {
                    int dj = c - 32;
                    int v = row >> 3, b = row & 7;
                    float e = acc2[i][j];
                    float vp = verts[((size_t)b * NV + v) * 3 + dj];
                    float* orow = out + ((size_t)b * NV + v) * 38;
                    orow[32 + dj] = (vp + e) * 1000.f;
                    orow[35 + dj] = e * 1000.f;
                }
            }
        }
    }
}

// gather-agg over y2 (32-wide x 8 batches = 256 floats/vertex); write out[0..31]
__global__ void k_agg2(const int* __restrict__ counts, const int* __restrict__ offs,
                       const int* __restrict__ csr, const float* __restrict__ y2,
                       float* __restrict__ out) {
    int wid = (blockIdx.x * 256 + threadIdx.x) >> 6;   // vertex
    int l = threadIdx.x & 63;
    if (wid >= NV) return;
    int beg = offs[wid], n = counts[wid];
    float ax = 0.f, ay = 0.f, az = 0.f, aw = 0.f;
    for (int j = 0; j < n; j++) {
        int c = csr[beg + j];
        const float4* src = (const float4*)(y2 + (size_t)c * 256);
        float4 u = src[l];
        ax += u.x; ay += u.y; az += u.z; aw += u.w;
    }
    float dinv = 1.f / fmaxf((float)n, 1.f);
    int b = l >> 3, o = (l & 7) * 4;
    float* orow = out + ((size_t)b * NV + wid) * 38 + o;
    orow[0] = ax * dinv;
    orow[1] = ay * dinv;
    orow[2] = az * dinv;
    orow[3] = aw * dinv;
}

extern "C" void kernel_launch(void* const* d_in, const int* in_sizes, int n_in,
                              void* d_out, int out_size, void* d_ws, size_t ws_size,
                              hipStream_t stream) {
    const float* fm  = (const float*)d_in[0];
    const float* dm  = (const float*)d_in[1];
    const float* vt  = (const float*)d_in[2];
    const float* fz  = (const float*)d_in[3];
    const float* cz  = (const float*)d_in[4];
    const float* cw  = (const float*)d_in[5];
    const float* cb  = (const float*)d_in[6];
    const float* W1  = (const float*)d_in[7];
    const float* b1  = (const float*)d_in[8];
    const float* W2  = (const float*)d_in[9];
    const float* Wdv = (const float*)d_in[10];
    const int* erow  = (const int*)d_in[11];
    const int* ecol  = (const int*)d_in[12];
    float* out = (float*)d_out;

    float* ws    = (float*)d_ws;
    float* pf    = ws;                   // 2097152
    float* xfeat = pf + 2097152;         // 6291456
    float* agg1d = xfeat + 6291456;      // 6291456
    float* y2    = agg1d + 6291456;      // 3145728
    float* cwT   = y2 + 3145728;         // 24576
    int* counts  = (int*)(cwT + 24576);  // 12288
    int* offs    = counts + 12288;       // 12288
    int* cursor  = offs + 12288;         // 12288
    int* csr     = cursor + 12288;       // 147456

    hipMemsetAsync(counts, 0, 12288 * sizeof(int), stream);
    hipMemsetAsync(cursor, 0, 12288 * sizeof(int), stream);

    k_wt<<<96, 256, 0, stream>>>(cw, cwT);
    k_conv<<<512, 256, 0, stream>>>(fm, cwT, pf);
    k_sample<<<6144, 256, 0, stream>>>(dm, pf, vt, fz, cz, cb, xfeat);
    k_count<<<576, 256, 0, stream>>>(erow, counts);
    k_scan<<<1, 1024, 0, stream>>>(counts, offs);
    k_fill<<<576, 256, 0, stream>>>(erow, ecol, offs, cursor, csr);
    k_agg1<<<3072, 256, 0, stream>>>(counts, offs, csr, xfeat, agg1d);
    k_mlp<<<1536, 256, 0, stream>>>(agg1d, W1, b1, W2, Wdv, vt, y2, out);
    k_agg2<<<3072, 256, 0, stream>>>(counts, offs, csr, y2, out);
}

// Round 6
// 205.648 us; speedup vs baseline: 5.6398x; 1.2710x over previous
//
#include <hip/hip_runtime.h>

#define NB 8
#define NV 12288
#define NE 147456
#define CFM 384
#define CU 61
#define FEPS 0.005f

// ---------- ws layout ----------
// pf    : NB*4096*64 f  = 2097152   (conv-projected feature map, [b][p][64])
// xfeat : NV*NB*64 f    = 6291456   (vertex-major GNN input)
// agg1d : NV*NB*64 f    = 6291456   (gathered+divided)
// y2    : NV*NB*32 f    = 3145728   (h @ W2, vertex-major)
// cwT   : 384*64 f      = 24576
// counts: NV int, offs: NV int, cursor: NV int, csr: NE int

// transpose conv_w (61,384) -> cwT (384,64), zero-pad o>=61
__global__ void k_wt(const float* __restrict__ cw, float* __restrict__ cwT) {
    int idx = blockIdx.x * 256 + threadIdx.x;
    if (idx >= CFM * 64) return;
    int c = idx >> 6, o = idx & 63;
    cwT[idx] = (o < CU) ? cw[o * CFM + c] : 0.f;
}

// pf[b][p][o] = sum_c cwT[c][o] * fm[b][c][p]
// block = 256 threads = 64 positions x 4 output-groups of 16 (og FORCED uniform
// via readfirstlane -> weight loads become s_load through scalar cache)
__global__ __launch_bounds__(256) void k_conv(const float* __restrict__ fm,
                                              const float* __restrict__ cwT,
                                              float* __restrict__ pf) {
    __shared__ float ftile[32][64];   // 8 KB
    int tid = threadIdx.x;
    int lane = tid & 63;
    int og = __builtin_amdgcn_readfirstlane(tid >> 6);   // wave-uniform -> SGPR
    int idx0 = blockIdx.x * 64;
    int b = idx0 >> 12, p0 = idx0 & 4095;
    const float* fb = fm + (size_t)b * CFM * 4096 + p0;
    float acc[16];
#pragma unroll
    for (int o = 0; o < 16; o++) acc[o] = 0.f;
    for (int cc = 0; cc < CFM; cc += 32) {
        // stage 32x64 fm tile as float4: 512 float4, 2 per thread, coalesced
#pragma unroll
        for (int i = 0; i < 2; i++) {
            int lin = tid + 256 * i;              // 0..511
            int c = lin >> 4, pq = lin & 15;      // 16 float4 per c-row
            *(float4*)&ftile[c][pq * 4] =
                *(const float4*)(fb + (size_t)(cc + c) * 4096 + pq * 4);
        }
        __syncthreads();
#pragma unroll 8
        for (int c = 0; c < 32; c++) {
            float fv = ftile[c][lane];
            const float4* w4 = (const float4*)(cwT + (cc + c) * 64 + og * 16);
            float4 wa = w4[0], wb = w4[1], wc = w4[2], wd = w4[3];
            float w[16] = {wa.x, wa.y, wa.z, wa.w, wb.x, wb.y, wb.z, wb.w,
                           wc.x, wc.y, wc.z, wc.w, wd.x, wd.y, wd.z, wd.w};
#pragma unroll
            for (int o = 0; o < 16; o++) acc[o] = fmaf(fv, w[o], acc[o]);
        }
        __syncthreads();
    }
    float4* outp = (float4*)(pf + (size_t)(idx0 + lane) * 64 + og * 16);
#pragma unroll
    for (int o4 = 0; o4 < 4; o4++)
        outp[o4] = make_float4(acc[o4 * 4], acc[o4 * 4 + 1], acc[o4 * 4 + 2], acc[o4 * 4 + 3]);
}

// per-vertex projection + depth visibility + feature bilinear -> xfeat[v][b][64]
__global__ void k_sample(const float* __restrict__ depth, const float* __restrict__ pf,
                         const float* __restrict__ verts, const float* __restrict__ fz,
                         const float* __restrict__ cz, const float* __restrict__ convb,
                         float* __restrict__ xfeat) {
    int t = blockIdx.x * 256 + threadIdx.x;
    int gid = t >> 4;                 // b*NV+v
    int ln = t & 15;
    int b = gid / NV;
    int v = gid - b * NV;
    const float* vp = verts + (size_t)gid * 3;
    float vx = vp[0], vy = vp[1], vz = vp[2];
    float fzb = fz[b], czb = cz[2 * b];
    float gx = fzb * vx + czb;
    float gy = fzb * vy + czb;
    float gz = fzb * (vz + 100.f);

    float px = (gx + 1.f) * 64.f - 0.5f;
    float py = (gy + 1.f) * 64.f - 0.5f;
    float fx0 = floorf(px), fy0 = floorf(py);
    float wx1 = px - fx0, wy1 = py - fy0, wx0 = 1.f - wx1, wy0 = 1.f - wy1;
    int x0 = (int)fx0, y0 = (int)fy0;
    const float* dmb = depth + (size_t)b * 128 * 128;
    float d00 = 0.f, d01 = 0.f, d10 = 0.f, d11 = 0.f;
    bool X0 = (x0 >= 0 && x0 < 128), X1 = (x0 + 1 >= 0 && x0 + 1 < 128);
    bool Y0 = (y0 >= 0 && y0 < 128), Y1 = (y0 + 1 >= 0 && y0 + 1 < 128);
    int xa = min(max(x0, 0), 127), xb = min(max(x0 + 1, 0), 127);
    int ya = min(max(y0, 0), 127), yb = min(max(y0 + 1, 0), 127);
    if (Y0 && X0) d00 = dmb[ya * 128 + xa];
    if (Y0 && X1) d01 = dmb[ya * 128 + xb];
    if (Y1 && X0) d10 = dmb[yb * 128 + xa];
    if (Y1 && X1) d11 = dmb[yb * 128 + xb];
    float sd = d00 * wy0 * wx0 + d01 * wy0 * wx1 + d10 * wy1 * wx0 + d11 * wy1 * wx1;
    float vis = (fabsf(sd - gz) < FEPS) ? 1.f : 0.f;

    float qx = (gx + 1.f) * 32.f - 0.5f;
    float qy = (gy + 1.f) * 32.f - 0.5f;
    float gx0 = floorf(qx), gy0 = floorf(qy);
    float ax1 = qx - gx0, ay1 = qy - gy0, ax0 = 1.f - ax1, ay0 = 1.f - ay1;
    int cx0 = (int)gx0, cy0 = (int)gy0;
    bool FX0 = (cx0 >= 0 && cx0 < 64), FX1 = (cx0 + 1 >= 0 && cx0 + 1 < 64);
    bool FY0 = (cy0 >= 0 && cy0 < 64), FY1 = (cy0 + 1 >= 0 && cy0 + 1 < 64);
    int fxa = min(max(cx0, 0), 63), fxb = min(max(cx0 + 1, 0), 63);
    int fya = min(max(cy0, 0), 63), fyb = min(max(cy0 + 1, 0), 63);
    float m00 = (FY0 && FX0) ? ay0 * ax0 : 0.f;
    float m01 = (FY0 && FX1) ? ay0 * ax1 : 0.f;
    float m10 = (FY1 && FX0) ? ay1 * ax0 : 0.f;
    float m11 = (FY1 && FX1) ? ay1 * ax1 : 0.f;
    const float* pfb = pf + (size_t)b * 4096 * 64;
    const float* p00 = pfb + ((size_t)fya * 64 + fxa) * 64;
    const float* p01 = pfb + ((size_t)fya * 64 + fxb) * 64;
    const float* p10 = pfb + ((size_t)fyb * 64 + fxa) * 64;
    const float* p11 = pfb + ((size_t)fyb * 64 + fxb) * 64;

    float* xr = xfeat + ((size_t)v * NB + b) * 64;
#pragma unroll
    for (int j = 0; j < 4; j++) {
        int c = ln + 16 * j;
        if (c < CU) {
            float val = m00 * p00[c] + m01 * p01[c] + m10 * p10[c] + m11 * p11[c];
            xr[c] = vis * val + convb[c];
        } else {
            xr[c] = vp[c - CU];
        }
    }
}

// ---- CSR build ----
__global__ void k_count(const int* __restrict__ erow, int* __restrict__ counts) {
    int e = blockIdx.x * 256 + threadIdx.x;
    if (e < NE) atomicAdd(&counts[erow[e]], 1);
}

__global__ void k_scan(const int* __restrict__ counts, int* __restrict__ offs) {
    __shared__ int part[1024];
    int t = threadIdx.x;
    int base = t * 12;
    int local[12];
    int s = 0;
#pragma unroll
    for (int i = 0; i < 12; i++) { local[i] = s; s += counts[base + i]; }
    part[t] = s;
    __syncthreads();
    for (int off = 1; off < 1024; off <<= 1) {
        int v = (t >= off) ? part[t - off] : 0;
        __syncthreads();
        part[t] += v;
        __syncthreads();
    }
    int prefix = part[t] - s;   // exclusive
#pragma unroll
    for (int i = 0; i < 12; i++) offs[base + i] = prefix + local[i];
}

__global__ void k_fill(const int* __restrict__ erow, const int* __restrict__ ecol,
                       const int* __restrict__ offs, int* __restrict__ cursor,
                       int* __restrict__ csr) {
    int e = blockIdx.x * 256 + threadIdx.x;
    if (e >= NE) return;
    int r = erow[e];
    int pos = offs[r] + atomicAdd(&cursor[r], 1);
    csr[pos] = ecol[e];
}

// gather-agg 64-wide over all 8 batches; one wave per dest vertex; fold 1/deg
__global__ void k_agg1(const int* __restrict__ counts, const int* __restrict__ offs,
                       const int* __restrict__ csr, const float* __restrict__ xfeat,
                       float* __restrict__ agg1d) {
    int wid = (blockIdx.x * 256 + threadIdx.x) >> 6;   // vertex
    int l = threadIdx.x & 63;
    if (wid >= NV) return;
    int beg = offs[wid], n = counts[wid];
    float a0x = 0.f, a0y = 0.f, a0z = 0.f, a0w = 0.f;
    float a1x = 0.f, a1y = 0.f, a1z = 0.f, a1w = 0.f;
    for (int j = 0; j < n; j++) {
        int c = csr[beg + j];
        const float4* src = (const float4*)(xfeat + (size_t)c * 512);
        float4 u = src[l];
        float4 w = src[64 + l];
        a0x += u.x; a0y += u.y; a0z += u.z; a0w += u.w;
        a1x += w.x; a1y += w.y; a1z += w.z; a1w += w.w;
    }
    float dinv = 1.f / fmaxf((float)n, 1.f);
    float4* dst = (float4*)(agg1d + (size_t)wid * 512);
    dst[l]      = make_float4(a0x * dinv, a0y * dinv, a0z * dinv, a0w * dinv);
    dst[64 + l] = make_float4(a1x * dinv, a1y * dinv, a1z * dinv, a1w * dinv);
}

// fused MLP, register-tiled. Block=256, M-tile=64 rows (row = v*8+b).
__global__ __launch_bounds__(256) void k_mlp(
        const float* __restrict__ agg1d, const float* __restrict__ W1,
        const float* __restrict__ b1, const float* __restrict__ W2,
        const float* __restrict__ Wdv, const float* __restrict__ verts,
        float* __restrict__ y2, float* __restrict__ out) {
    __shared__ float lds[13440];      // 53760 B
    float* xT   = lds;                // [64][64]   = 4096 f
    float* w1s  = lds + 4096;         // [64][128]  = 8192 f
    float* hlds = lds;                // [128][68]  = 8704 f (phase 2)
    float* w2e  = lds + 8704;         // [128][36]  = 4608 f (phase 2)
    float* b1s  = lds + 13312;        // [128]

    int tid = threadIdx.x;
    int r = tid & 63, q = tid >> 6;
    int base = blockIdx.x * 64;

    if (tid < 128) b1s[tid] = b1[tid];
    {
        const float4* arow = (const float4*)(agg1d + (size_t)(base + r) * 64 + q * 16);
#pragma unroll
        for (int i = 0; i < 4; i++) {
            float4 u = arow[i];
            int k0 = q * 16 + i * 4;
            xT[(k0 + 0) * 64 + r] = u.x;
            xT[(k0 + 1) * 64 + r] = u.y;
            xT[(k0 + 2) * 64 + r] = u.z;
            xT[(k0 + 3) * 64 + r] = u.w;
        }
    }
    {
        const float4* wsrc = (const float4*)W1;
        float4* wdst = (float4*)w1s;
#pragma unroll
        for (int i = 0; i < 8; i++) {
            int idx = tid + 256 * i;
            wdst[idx] = wsrc[idx];
        }
    }
    __syncthreads();

    int rg = tid & 15, cg = tid >> 4;
    int r0 = rg * 4, c0 = cg * 8;
    float acc[4][8];
#pragma unroll
    for (int i = 0; i < 4; i++)
#pragma unroll
        for (int j = 0; j < 8; j++) acc[i][j] = 0.f;
#pragma unroll 4
    for (int k = 0; k < 64; k++) {
        float4 xv = *(const float4*)(xT + k * 64 + r0);
        float4 wa = *(const float4*)(w1s + k * 128 + c0);
        float4 wb = *(const float4*)(w1s + k * 128 + c0 + 4);
        float xr_[4] = {xv.x, xv.y, xv.z, xv.w};
        float wr_[8] = {wa.x, wa.y, wa.z, wa.w, wb.x, wb.y, wb.z, wb.w};
#pragma unroll
        for (int i = 0; i < 4; i++)
#pragma unroll
            for (int j = 0; j < 8; j++)
                acc[i][j] = fmaf(xr_[i], wr_[j], acc[i][j]);
    }
    float bv[8];
#pragma unroll
    for (int j = 0; j < 8; j++) bv[j] = b1s[c0 + j];
    __syncthreads();

#pragma unroll
    for (int j = 0; j < 8; j++)
#pragma unroll
        for (int i = 0; i < 4; i++)
            hlds[(c0 + j) * 68 + r0 + i] = fmaxf(acc[i][j] + bv[j], 0.f);
#pragma unroll
    for (int i = 0; i < 18; i++) {
        int idx = tid + 256 * i;
        int k = idx / 36, c = idx - k * 36;
        float val = (c < 32) ? W2[k * 32 + c] : ((c < 35) ? Wdv[k * 3 + (c - 32)] : 0.f);
        w2e[idx] = val;
    }
    __syncthreads();

    int cg2 = tid >> 4;
    int c2 = cg2 * 3;
    if (cg2 < 12) {
        float acc2[4][3];
#pragma unroll
        for (int i = 0; i < 4; i++)
#pragma unroll
            for (int j = 0; j < 3; j++) acc2[i][j] = 0.f;
#pragma unroll 4
        for (int k = 0; k < 128; k++) {
            float4 hv = *(const float4*)(hlds + k * 68 + r0);
            float hr_[4] = {hv.x, hv.y, hv.z, hv.w};
            float w0 = w2e[k * 36 + c2];
            float w1v = w2e[k * 36 + c2 + 1];
            float w2v = w2e[k * 36 + c2 + 2];
#pragma unroll
            for (int i = 0; i < 4; i++) {
                acc2[i][0] = fmaf(hr_[i], w0, acc2[i][0]);
                acc2[i][1] = fmaf(hr_[i], w1v, acc2[i][1]);
                acc2[i][2] = fmaf(hr_[i], w2v, acc2[i][2]);
            }
        }
#pragma unroll
        for (int i = 0; i < 4; i++) {
            int row = base + r0 + i;
#pragma unroll
            for (int j = 0; j < 3; j++) {
                int c = c2 + j;
                if (c < 32) {
                    y2[(size_t)row * 32 + c] = acc2[i][j];
                } else if (c < 35) {
                    int dj = c - 32;
                    int v = row >> 3, b = row & 7;
                    float e = acc2[i][j];
                    float vp = verts[((size_t)b * NV + v) * 3 + dj];
                    float* orow = out + ((size_t)b * NV + v) * 38;
                    orow[32 + dj] = (vp + e) * 1000.f;
                    orow[35 + dj] = e * 1000.f;
                }
            }
        }
    }
}

// gather-agg over y2 (32-wide x 8 batches = 256 floats/vertex); write out[0..31]
__global__ void k_agg2(const int* __restrict__ counts, const int* __restrict__ offs,
                       const int* __restrict__ csr, const float* __restrict__ y2,
                       float* __restrict__ out) {
    int wid = (blockIdx.x * 256 + threadIdx.x) >> 6;   // vertex
    int l = threadIdx.x & 63;
    if (wid >= NV) return;
    int beg = offs[wid], n = counts[wid];
    float ax = 0.f, ay = 0.f, az = 0.f, aw = 0.f;
    for (int j = 0; j < n; j++) {
        int c = csr[beg + j];
        const float4* src = (const float4*)(y2 + (size_t)c * 256);
        float4 u = src[l];
        ax += u.x; ay += u.y; az += u.z; aw += u.w;
    }
    float dinv = 1.f / fmaxf((float)n, 1.f);
    int b = l >> 3, o = (l & 7) * 4;
    float* orow = out + ((size_t)b * NV + wid) * 38 + o;
    orow[0] = ax * dinv;
    orow[1] = ay * dinv;
    orow[2] = az * dinv;
    orow[3] = aw * dinv;
}

extern "C" void kernel_launch(void* const* d_in, const int* in_sizes, int n_in,
                              void* d_out, int out_size, void* d_ws, size_t ws_size,
                              hipStream_t stream) {
    const float* fm  = (const float*)d_in[0];
    const float* dm  = (const float*)d_in[1];
    const float* vt  = (const float*)d_in[2];
    const float* fz  = (const float*)d_in[3];
    const float* cz  = (const float*)d_in[4];
    const float* cw  = (const float*)d_in[5];
    const float* cb  = (const float*)d_in[6];
    const float* W1  = (const float*)d_in[7];
    const float* b1  = (const float*)d_in[8];
    const float* W2  = (const float*)d_in[9];
    const float* Wdv = (const float*)d_in[10];
    const int* erow  = (const int*)d_in[11];
    const int* ecol  = (const int*)d_in[12];
    float* out = (float*)d_out;

    float* ws    = (float*)d_ws;
    float* pf    = ws;                   // 2097152
    float* xfeat = pf + 2097152;         // 6291456
    float* agg1d = xfeat + 6291456;      // 6291456
    float* y2    = agg1d + 6291456;      // 3145728
    float* cwT   = y2 + 3145728;         // 24576
    int* counts  = (int*)(cwT + 24576);  // 12288
    int* offs    = counts + 12288;       // 12288
    int* cursor  = offs + 12288;         // 12288
    int* csr     = cursor + 12288;       // 147456

    hipMemsetAsync(counts, 0, 12288 * sizeof(int), stream);
    hipMemsetAsync(cursor, 0, 12288 * sizeof(int), stream);

    k_wt<<<96, 256, 0, stream>>>(cw, cwT);
    k_conv<<<512, 256, 0, stream>>>(fm, cwT, pf);
    k_sample<<<6144, 256, 0, stream>>>(dm, pf, vt, fz, cz, cb, xfeat);
    k_count<<<576, 256, 0, stream>>>(erow, counts);
    k_scan<<<1, 1024, 0, stream>>>(counts, offs);
    k_fill<<<576, 256, 0, stream>>>(erow, ecol, offs, cursor, csr);
    k_agg1<<<3072, 256, 0, stream>>>(counts, offs, csr, xfeat, agg1d);
    k_mlp<<<1536, 256, 0, stream>>>(agg1d, W1, b1, W2, Wdv, vt, y2, out);
    k_agg2<<<3072, 256, 0, stream>>>(counts, offs, csr, y2, out);
}